// Round 17
// baseline (151.328 us; speedup 1.0000x reference)
//
#include <hip/hip_runtime.h>

#define NN 50000
#define NNP 50048  // padded row count (multiple of 64) for MFMA kernels
#define NE 800000
#define DF 128     // H * D_HID == D_IN
#define BCAP 64    // per-node edge bucket capacity (deg ~ Poisson(16): P(>64) ~ 0)
#define NCHUNK (NE / 256)              // 3125 edge chunks of 256
#define HB_PER_RANGE 512               // hist blocks per dst-range
#define HF_BLOCKS (HB_PER_RANGE * 8)   // 4096 grid-strided hist blocks
#define PROJ_BLOCKS ((NN + 63) / 64)   // 782 (64-row tiles)

typedef __attribute__((ext_vector_type(8))) short short8v;    // 8 bf16 (4 VGPRs)
typedef __attribute__((ext_vector_type(4))) float float4v;    // MFMA acc
typedef __attribute__((ext_vector_type(2))) _Float16 half2v;  // packed fp16 pair

__device__ __forceinline__ float leaky(float t) { return fmaxf(t, 0.2f * t); }

__device__ __forceinline__ unsigned short rne_bf16(float x) {
  unsigned u = __float_as_uint(x);
  u = (u + 0x7fffu + ((u >> 16) & 1u)) >> 16;
  return (unsigned short)u;
}

// f32 add over DPP lane-permute (full-rate VALU; avoids ds_bpermute latency)
template <int CTRL>
__device__ __forceinline__ float dpp_add(float v) {
  const int i = __builtin_bit_cast(int, v);
  const int p = __builtin_amdgcn_update_dpp(0, i, CTRL, 0xF, 0xF, true);
  return v + __builtin_bit_cast(float, p);
}
// sum over 8 contiguous lanes: xor1 (0xB1), xor2 (0x4E), row_half_mirror (0x141)
__device__ __forceinline__ float reduce8_dpp(float v) {
  v = dpp_add<0xB1>(v);
  v = dpp_add<0x4E>(v);
  v = dpp_add<0x141>(v);
  return v;
}

// ---------------- prep: zero deg + ALL weight casts (WT0 must precede proj L0) -------
// blocks [0,196) zero deg; [196,452) WT casts; [452,476) RT casts
__global__ void prep_kernel(int* __restrict__ deg,
                            const float* __restrict__ Ws0, const float* __restrict__ Wd0,
                            const float* __restrict__ Ws1, const float* __restrict__ Wd1,
                            unsigned short* __restrict__ WT0, unsigned short* __restrict__ WT1,
                            const float* __restrict__ R0W, const float* __restrict__ R1W,
                            const float* __restrict__ R2W, unsigned short* __restrict__ RT) {
  const int b = blockIdx.x;
  const int tid = threadIdx.x;
  if (b < 196) {
    const int i = b * 256 + tid;
    if (i < NN) deg[i] = 0;
  } else if (b < 452) {                // WT[l][256][128]: row c<128 -> Wsrc col c, else Wdst
    const int idx = (b - 196) * 256 + tid;   // 0..65535
    const int l = idx >> 15;
    const int r = (idx >> 7) & 255;
    const int k = idx & 127;
    const float* Ws = l ? Ws1 : Ws0;
    const float* Wd = l ? Wd1 : Wd0;
    const float v = (r < 128) ? Ws[k * DF + r] : Wd[k * DF + (r - 128)];
    (l ? WT1 : WT0)[r * DF + k] = rne_bf16(v);
  } else {                             // RT[16][384]
    const int idx = (b - 452) * 256 + tid;   // 0..6143
    const int c = idx / 384, k = idx - c * 384;
    const float* Rw = (k < 128) ? R0W : (k < 256) ? R1W : R2W;
    RT[c * 384 + k] = rne_bf16(Rw[(k & 127) * 16 + c]);
  }
}

// ---------------- shared MFMA projection body, 64-row tiles ----------------
// L0: f32 input + xb write-through. 4 waves x 64 cols each; 4 row-tiles of 16.
template <bool L0>
__device__ __forceinline__ void proj_body(unsigned short (*At)[136], int blk, int tid,
                                          const unsigned short* __restrict__ Ab,
                                          const float* __restrict__ Xf,
                                          unsigned short* __restrict__ XbOut,
                                          const unsigned short* __restrict__ WT,
                                          _Float16* __restrict__ fsh,
                                          _Float16* __restrict__ fdh) {
  const int w = tid >> 6, l = tid & 63;

#pragma unroll
  for (int i = 0; i < 4; ++i) {
    const int flat = i * 256 + tid;
    const int r = flat >> 4, c16 = flat & 15;
    const int row = blk * 64 + r;
    uint4 v = make_uint4(0, 0, 0, 0);
    if (L0) {
      if (row < NN) {
        const float4 a = ((const float4*)Xf)[row * 32 + c16 * 2];
        const float4 bq = ((const float4*)Xf)[row * 32 + c16 * 2 + 1];
        v.x = rne_bf16(a.x) | ((unsigned)rne_bf16(a.y) << 16);
        v.y = rne_bf16(a.z) | ((unsigned)rne_bf16(a.w) << 16);
        v.z = rne_bf16(bq.x) | ((unsigned)rne_bf16(bq.y) << 16);
        v.w = rne_bf16(bq.z) | ((unsigned)rne_bf16(bq.w) << 16);
        ((uint4*)XbOut)[row * 16 + c16] = v;   // write-through for readout h0
      }
    } else {
      if (row < NN) v = ((const uint4*)Ab)[row * 16 + c16];
    }
    *(uint4*)&At[r][c16 * 8] = v;
  }

  const int kof = (l >> 4) * 8;
  const int cbase = w * 64 + (l & 15);
  short8v b[4][4];
#pragma unroll
  for (int ct = 0; ct < 4; ++ct)
#pragma unroll
    for (int kk = 0; kk < 4; ++kk)
      b[ct][kk] = *(const short8v*)(WT + (cbase + ct * 16) * DF + kk * 32 + kof);
  __syncthreads();

  const int lrow = l & 15;
#pragma unroll
  for (int rt = 0; rt < 4; ++rt) {
    short8v a[4];
#pragma unroll
    for (int kk = 0; kk < 4; ++kk) a[kk] = *(const short8v*)&At[rt * 16 + lrow][kk * 32 + kof];
    const int r0 = blk * 64 + rt * 16 + (l >> 4) * 4;
#pragma unroll
    for (int ct = 0; ct < 4; ++ct) {
      float4v acc = {0.f, 0.f, 0.f, 0.f};
#pragma unroll
      for (int kk = 0; kk < 4; ++kk)
        acc = __builtin_amdgcn_mfma_f32_16x16x32_bf16(a[kk], b[ct][kk], acc, 0, 0, 0);
      const int col = cbase + ct * 16;
      _Float16* O = (col < DF) ? fsh : fdh;
      const int c2 = (col < DF) ? col : col - DF;
#pragma unroll
      for (int r = 0; r < 4; ++r)
        if (r0 + r < NN) O[(r0 + r) * DF + c2] = (_Float16)acc[r];
    }
  }
}

// ---------------- stage1: proj L0 first, then GRID-STRIDED hist (XCD-ranged) ---------
// Proj blocks [0, PROJ_BLOCKS) start at t=0 on the MFMA pipe. Hist blocks
// [PROJ_BLOCKS, +HF_BLOCKS): range = b & 7 (== XCD via round-robin dispatch);
// each block LOOPS over its range's edge chunks (chunk = hb>>3 + j*HB_PER_RANGE),
// amortizing load latency across iterations instead of paying it per-workgroup.
__global__ __launch_bounds__(256) void stage1_kernel(
    const int* __restrict__ src, const int* __restrict__ dst, int* __restrict__ deg,
    unsigned short* __restrict__ ssrcB, const float* __restrict__ Xf,
    unsigned short* __restrict__ XbOut, const unsigned short* __restrict__ WT0,
    _Float16* __restrict__ fsh, _Float16* __restrict__ fdh) {
  __shared__ unsigned short At[64][136];
  const int b = blockIdx.x;
  const int tid = threadIdx.x;
  if (b >= PROJ_BLOCKS) {
    const int range = b & 7;                       // XCD id (blockIdx round-robin)
    const int rlo = range * 6250, rhi = rlo + 6250;
    const int hb = b - PROJ_BLOCKS;
    for (int c = hb >> 3; c < NCHUNK; c += HB_PER_RANGE) {
      const int e = c * 256 + tid;
      const int dn = dst[e];
      const int sv = src[e];           // coalesced read before divergence
      if (dn >= rlo && dn < rhi) {
        const int k = atomicAdd(&deg[dn], 1);
        if (k < BCAP) ssrcB[dn * BCAP + k] = (unsigned short)sv;
      }
    }
    return;
  }
  proj_body<true>(At, b, tid, nullptr, Xf, XbOut, WT0, fsh, fdh);
}

// ---------------- layer-1 projection (bf16 input) ----------------
__global__ __launch_bounds__(256) void proj_mfma_kernel(const unsigned short* __restrict__ Ab,
                                                        const unsigned short* __restrict__ WT,
                                                        _Float16* __restrict__ fsh,
                                                        _Float16* __restrict__ fdh) {
  __shared__ unsigned short At[64][136];
  proj_body<false>(At, blockIdx.x, threadIdx.x, Ab, nullptr, nullptr, WT, fsh, fdh);
}

// ---------------- fused attention (fp16, depth-2 rotation-free pipeline, DPP reduce) --
// One wave per node, both heads. lane = eg(2b)|s16(4b): 16B fp16 load = 8 dims;
// 16 lanes cover 128 dims. Prefetch indices UNCLAMPED (worst over-read sb[79] ->
// neighbor buckets / pad after ssrcB; any u16 row index gathers inside the 25.6 MB
// fsh+fdh region; junk discarded by the tail guard). Logit reduce = 3 DPP adds.
__global__ __launch_bounds__(256) void csr_attention_kernel(
    const _Float16* __restrict__ fsh, const _Float16* __restrict__ fdh,
    const float* __restrict__ attn, const int* __restrict__ degv,
    const unsigned short* __restrict__ ssrcB, const float* __restrict__ bias,
    unsigned short* __restrict__ houtb) {
  const int node = (blockIdx.x * 256 + threadIdx.x) >> 6;
  const int lane = threadIdx.x & 63;
  const int eg = lane >> 4, s16 = lane & 15;
  const int deg = min(degv[node], BCAP);
  const unsigned short* __restrict__ sb = ssrcB + node * BCAP;
  const uint4* __restrict__ fsh4 = (const uint4*)fsh;

  half2v fdv[4], at[4];
  {
    const uint4 fq = ((const uint4*)fdh)[node * 16 + s16];
    fdv[0] = __builtin_bit_cast(half2v, fq.x);
    fdv[1] = __builtin_bit_cast(half2v, fq.y);
    fdv[2] = __builtin_bit_cast(half2v, fq.z);
    fdv[3] = __builtin_bit_cast(half2v, fq.w);
    const float4 a0 = ((const float4*)(attn + s16 * 8))[0];
    const float4 a1 = ((const float4*)(attn + s16 * 8))[1];
    const float l2e = 1.44269504f;
    at[0] = (half2v){(_Float16)(a0.x * l2e), (_Float16)(a0.y * l2e)};
    at[1] = (half2v){(_Float16)(a0.z * l2e), (_Float16)(a0.w * l2e)};
    at[2] = (half2v){(_Float16)(a1.x * l2e), (_Float16)(a1.y * l2e)};
    at[3] = (half2v){(_Float16)(a1.z * l2e), (_Float16)(a1.w * l2e)};
  }
  const half2v c02 = {(_Float16)0.2f, (_Float16)0.2f};

  float s = 0.f;
  half2v acc[4] = {{0, 0}, {0, 0}, {0, 0}, {0, 0}};
  const int nfull = deg >> 2;
  const int rem = deg & 3;

  auto consume = [&](const uint4 q) {
    half2v f[4];
    f[0] = __builtin_bit_cast(half2v, q.x);
    f[1] = __builtin_bit_cast(half2v, q.y);
    f[2] = __builtin_bit_cast(half2v, q.z);
    f[3] = __builtin_bit_cast(half2v, q.w);
    float v = 0.f;
#pragma unroll
    for (int k = 0; k < 4; ++k) {
      const half2v t = f[k] + fdv[k];                            // v_pk_add_f16
      const half2v lk = __builtin_elementwise_max(t, t * c02);   // pk_mul + pk_max
      v = __builtin_amdgcn_fdot2(lk, at[k], v, false);           // v_dot2_f32_f16
    }
    v = reduce8_dpp(v);                                          // 3 VALU-dpp adds
    const float p = exp2f(v);
    s += p;
    const _Float16 ph = (_Float16)p;
    const half2v p2 = {ph, ph};
#pragma unroll
    for (int k = 0; k < 4; ++k) acc[k] = p2 * f[k] + acc[k];     // v_pk_fma_f16
  };

  // primer: rows for iters 0,1 in flight; indices for iters 2,3 loaded
  int snA = (int)sb[eg];
  int snB = (int)sb[eg + 4];
  uint4 qA = fsh4[snA * 16 + s16];
  uint4 qB = fsh4[snB * 16 + s16];
  snA = (int)sb[eg + 8];
  snB = (int)sb[eg + 12];

  int base = eg + 16;
  const int npairs = nfull >> 1;
  for (int jj = 0; jj < npairs; ++jj) {
    consume(qA);
    qA = fsh4[snA * 16 + s16];                 // row for iter 2j+2
    snA = (int)sb[base];                       // index for iter 2j+4 (may over-read)
    consume(qB);
    qB = fsh4[snB * 16 + s16];                 // row for iter 2j+3
    snB = (int)sb[base + 4];                   // index for iter 2j+5 (may over-read)
    base += 8;
  }
  if (nfull & 1) {  // peel the odd full iteration; tail row then sits in qB
    consume(qA);
    qA = qB;
  }
  if (rem) {  // tail: qA holds row for edge eg + 4*nfull (junk-but-finite if eg >= rem)
    half2v f[4];
    f[0] = __builtin_bit_cast(half2v, qA.x);
    f[1] = __builtin_bit_cast(half2v, qA.y);
    f[2] = __builtin_bit_cast(half2v, qA.z);
    f[3] = __builtin_bit_cast(half2v, qA.w);
    float v = 0.f;
#pragma unroll
    for (int k = 0; k < 4; ++k) {
      const half2v t = f[k] + fdv[k];
      const half2v lk = __builtin_elementwise_max(t, t * c02);
      v = __builtin_amdgcn_fdot2(lk, at[k], v, false);
    }
    v = reduce8_dpp(v);
    const float p = (eg < rem) ? exp2f(v) : 0.f;                 // guard zeroes junk
    s += p;
    const _Float16 ph = (_Float16)p;
    const half2v p2 = {ph, ph};
#pragma unroll
    for (int k = 0; k < 4; ++k) acc[k] = p2 * f[k] + acc[k];
  }

  // merge the 4 edge groups (one 32-bit shfl moves 2 dims)
#pragma unroll
  for (int dist = 16; dist <= 32; dist <<= 1) {
    s += __shfl_xor(s, dist);
#pragma unroll
    for (int k = 0; k < 4; ++k) {
      const float of = __shfl_xor(__builtin_bit_cast(float, acc[k]), dist);
      acc[k] = acc[k] + __builtin_bit_cast(half2v, of);
    }
  }

  if (lane < 16) {
    const float rs = (deg > 0) ? 1.0f / s : 0.0f;
    const float4 b0 = ((const float4*)(bias + s16 * 8))[0];
    const float4 b1 = ((const float4*)(bias + s16 * 8))[1];
    const float bb[8] = {b0.x, b0.y, b0.z, b0.w, b1.x, b1.y, b1.z, b1.w};
    float ob[8];
#pragma unroll
    for (int k = 0; k < 4; ++k) {
      ob[2 * k]     = leaky(fmaf((float)acc[k].x, rs, bb[2 * k]));
      ob[2 * k + 1] = leaky(fmaf((float)acc[k].y, rs, bb[2 * k + 1]));
    }
    uint4 w;
    w.x = rne_bf16(ob[0]) | ((unsigned)rne_bf16(ob[1]) << 16);
    w.y = rne_bf16(ob[2]) | ((unsigned)rne_bf16(ob[3]) << 16);
    w.z = rne_bf16(ob[4]) | ((unsigned)rne_bf16(ob[5]) << 16);
    w.w = rne_bf16(ob[6]) | ((unsigned)rne_bf16(ob[7]) << 16);
    ((uint4*)houtb)[node * 16 + s16] = w;
  }
}

// ---------------- readout via MFMA: [h0|h1|h2] (Nx384) @ RT^T (384x16) ----------------
__global__ __launch_bounds__(256) void readout_mfma_kernel(
    const unsigned short* __restrict__ h0b, const unsigned short* __restrict__ h1b,
    const unsigned short* __restrict__ h2b, const unsigned short* __restrict__ RT,
    const float* __restrict__ R0b, const float* __restrict__ R1b,
    const float* __restrict__ R2b, float* __restrict__ out) {
  const int w = threadIdx.x >> 6, l = threadIdx.x & 63;
  const int row0 = blockIdx.x * 64 + w * 16;
  const int m = l & 15, ksub = (l >> 4) * 8;
  float4v acc = {0.f, 0.f, 0.f, 0.f};
  const unsigned short* hs[3] = {h0b, h1b, h2b};
#pragma unroll
  for (int a = 0; a < 3; ++a) {
    const unsigned short* __restrict__ H = hs[a];
#pragma unroll
    for (int kk = 0; kk < 4; ++kk) {
      const short8v av = *(const short8v*)(H + (size_t)(row0 + m) * DF + kk * 32 + ksub);
      const short8v bv = *(const short8v*)(RT + m * 384 + a * 128 + kk * 32 + ksub);
      acc = __builtin_amdgcn_mfma_f32_16x16x32_bf16(av, bv, acc, 0, 0, 0);
    }
  }
  const float rb = R0b[m] + R1b[m] + R2b[m];
  const int r0 = row0 + (l >> 4) * 4;
#pragma unroll
  for (int r = 0; r < 4; ++r)
    if (r0 + r < NN) out[(r0 + r) * 16 + m] = acc[r] + rb;
}

extern "C" void kernel_launch(void* const* d_in, const int* in_sizes, int n_in,
                              void* d_out, int out_size, void* d_ws, size_t ws_size,
                              hipStream_t stream) {
  const float* x     = (const float*)d_in[0];
  const int*   src   = (const int*)d_in[1];
  const int*   dst   = (const int*)d_in[2];
  const float* Wsrc0 = (const float*)d_in[3];
  const float* Wdst0 = (const float*)d_in[4];
  const float* attn0 = (const float*)d_in[5];
  const float* bias0 = (const float*)d_in[6];
  const float* Wsrc1 = (const float*)d_in[7];
  const float* Wdst1 = (const float*)d_in[8];
  const float* attn1 = (const float*)d_in[9];
  const float* bias1 = (const float*)d_in[10];
  const float* R0W   = (const float*)d_in[11];
  const float* R0b   = (const float*)d_in[12];
  const float* R1W   = (const float*)d_in[13];
  const float* R1b   = (const float*)d_in[14];
  const float* R2W   = (const float*)d_in[15];
  const float* R2b   = (const float*)d_in[16];
  float* out = (float*)d_out;

  // workspace: xb | h1b | h2b (NNP rows bf16) | fsh | fdh (NN rows fp16)
  //            | WT0 | WT1 | RT (bf16) | deg (int) | ssrcB (+512 pad, u16)   ~= 71 MB
  unsigned short* xb  = (unsigned short*)d_ws;
  unsigned short* h1b = xb + (size_t)NNP * DF;
  unsigned short* h2b = h1b + (size_t)NNP * DF;
  _Float16* fsh = (_Float16*)(h2b + (size_t)NNP * DF);
  _Float16* fdh = fsh + (size_t)NN * DF;
  unsigned short* WT0 = (unsigned short*)(fdh + (size_t)NN * DF);
  unsigned short* WT1 = WT0 + 256 * DF;
  unsigned short* RT  = WT1 + 256 * DF;
  int* deg = (int*)(RT + 16 * 384);
  unsigned short* ssrcB = (unsigned short*)(deg + NN);
  // (ssrcB spans NN*BCAP + 512-entry slack for unclamped prefetch over-reads)

  // ---- launch 1: zero deg + all weight casts (WT0 ready before stage1's proj) ----
  prep_kernel<<<476, 256, 0, stream>>>(deg, Wsrc0, Wdst0, Wsrc1, Wdst1, WT0, WT1,
                                       R0W, R1W, R2W, RT);

  // ---- launch 2: proj L0 (blocks 0..781) + grid-strided hist (XCD-ranged) ----
  stage1_kernel<<<PROJ_BLOCKS + HF_BLOCKS, 256, 0, stream>>>(
      src, dst, deg, ssrcB, x, xb, WT0, fsh, fdh);

  // ---- layer 0 attention ----
  csr_attention_kernel<<<(NN * 64) / 256, 256, 0, stream>>>(fsh, fdh, attn0, deg, ssrcB, bias0, h1b);
  // ---- layer 1 ----
  proj_mfma_kernel<<<PROJ_BLOCKS, 256, 0, stream>>>(h1b, WT1, fsh, fdh);
  csr_attention_kernel<<<(NN * 64) / 256, 256, 0, stream>>>(fsh, fdh, attn1, deg, ssrcB, bias1, h2b);

  // ---- readout ----
  readout_mfma_kernel<<<NNP / 64, 256, 0, stream>>>(xb, h1b, h2b, RT, R0b, R1b, R2b, out);
}

// Round 18
// 147.270 us; speedup vs baseline: 1.0276x; 1.0276x over previous
//
#include <hip/hip_runtime.h>

#define NN 50000
#define NNP 50048  // padded row count (multiple of 64) for MFMA kernels
#define NE 800000
#define DF 128     // H * D_HID == D_IN
#define BCAP 64    // per-node edge bucket capacity (deg ~ Poisson(16): P(>64) ~ 0)
#define NCHUNK (NE / 256)              // 3125 edge chunks of 256
#define HB_PER_RANGE 256               // hist blocks per dst-range (13 iters/block)
#define HF_BLOCKS (HB_PER_RANGE * 8)   // 2048 grid-strided hist blocks
#define PROJ_BLOCKS ((NN + 63) / 64)   // 782 (64-row tiles)

typedef __attribute__((ext_vector_type(8))) short short8v;    // 8 bf16 (4 VGPRs)
typedef __attribute__((ext_vector_type(4))) float float4v;    // MFMA acc
typedef __attribute__((ext_vector_type(2))) _Float16 half2v;  // packed fp16 pair

__device__ __forceinline__ float leaky(float t) { return fmaxf(t, 0.2f * t); }

__device__ __forceinline__ unsigned short rne_bf16(float x) {
  unsigned u = __float_as_uint(x);
  u = (u + 0x7fffu + ((u >> 16) & 1u)) >> 16;
  return (unsigned short)u;
}

// f32 add over DPP lane-permute (full-rate VALU; avoids ds_bpermute latency)
template <int CTRL>
__device__ __forceinline__ float dpp_add(float v) {
  const int i = __builtin_bit_cast(int, v);
  const int p = __builtin_amdgcn_update_dpp(0, i, CTRL, 0xF, 0xF, true);
  return v + __builtin_bit_cast(float, p);
}
// sum over 8 contiguous lanes: xor1 (0xB1), xor2 (0x4E), row_half_mirror (0x141)
__device__ __forceinline__ float reduce8_dpp(float v) {
  v = dpp_add<0xB1>(v);
  v = dpp_add<0x4E>(v);
  v = dpp_add<0x141>(v);
  return v;
}

// ---------------- prep: zero deg + ALL weight casts (WT0 must precede proj L0) -------
// blocks [0,196) zero deg; [196,452) WT casts; [452,476) RT casts
__global__ void prep_kernel(int* __restrict__ deg,
                            const float* __restrict__ Ws0, const float* __restrict__ Wd0,
                            const float* __restrict__ Ws1, const float* __restrict__ Wd1,
                            unsigned short* __restrict__ WT0, unsigned short* __restrict__ WT1,
                            const float* __restrict__ R0W, const float* __restrict__ R1W,
                            const float* __restrict__ R2W, unsigned short* __restrict__ RT) {
  const int b = blockIdx.x;
  const int tid = threadIdx.x;
  if (b < 196) {
    const int i = b * 256 + tid;
    if (i < NN) deg[i] = 0;
  } else if (b < 452) {                // WT[l][256][128]: row c<128 -> Wsrc col c, else Wdst
    const int idx = (b - 196) * 256 + tid;   // 0..65535
    const int l = idx >> 15;
    const int r = (idx >> 7) & 255;
    const int k = idx & 127;
    const float* Ws = l ? Ws1 : Ws0;
    const float* Wd = l ? Wd1 : Wd0;
    const float v = (r < 128) ? Ws[k * DF + r] : Wd[k * DF + (r - 128)];
    (l ? WT1 : WT0)[r * DF + k] = rne_bf16(v);
  } else {                             // RT[16][384]
    const int idx = (b - 452) * 256 + tid;   // 0..6143
    const int c = idx / 384, k = idx - c * 384;
    const float* Rw = (k < 128) ? R0W : (k < 256) ? R1W : R2W;
    RT[c * 384 + k] = rne_bf16(Rw[(k & 127) * 16 + c]);
  }
}

// ---------------- shared MFMA projection body, 64-row tiles ----------------
// L0: f32 input + xb write-through. 4 waves x 64 cols each; 4 row-tiles of 16.
template <bool L0>
__device__ __forceinline__ void proj_body(unsigned short (*At)[136], int blk, int tid,
                                          const unsigned short* __restrict__ Ab,
                                          const float* __restrict__ Xf,
                                          unsigned short* __restrict__ XbOut,
                                          const unsigned short* __restrict__ WT,
                                          _Float16* __restrict__ fsh,
                                          _Float16* __restrict__ fdh) {
  const int w = tid >> 6, l = tid & 63;

#pragma unroll
  for (int i = 0; i < 4; ++i) {
    const int flat = i * 256 + tid;
    const int r = flat >> 4, c16 = flat & 15;
    const int row = blk * 64 + r;
    uint4 v = make_uint4(0, 0, 0, 0);
    if (L0) {
      if (row < NN) {
        const float4 a = ((const float4*)Xf)[row * 32 + c16 * 2];
        const float4 bq = ((const float4*)Xf)[row * 32 + c16 * 2 + 1];
        v.x = rne_bf16(a.x) | ((unsigned)rne_bf16(a.y) << 16);
        v.y = rne_bf16(a.z) | ((unsigned)rne_bf16(a.w) << 16);
        v.z = rne_bf16(bq.x) | ((unsigned)rne_bf16(bq.y) << 16);
        v.w = rne_bf16(bq.z) | ((unsigned)rne_bf16(bq.w) << 16);
        ((uint4*)XbOut)[row * 16 + c16] = v;   // write-through for readout h0
      }
    } else {
      if (row < NN) v = ((const uint4*)Ab)[row * 16 + c16];
    }
    *(uint4*)&At[r][c16 * 8] = v;
  }

  const int kof = (l >> 4) * 8;
  const int cbase = w * 64 + (l & 15);
  short8v b[4][4];
#pragma unroll
  for (int ct = 0; ct < 4; ++ct)
#pragma unroll
    for (int kk = 0; kk < 4; ++kk)
      b[ct][kk] = *(const short8v*)(WT + (cbase + ct * 16) * DF + kk * 32 + kof);
  __syncthreads();

  const int lrow = l & 15;
#pragma unroll
  for (int rt = 0; rt < 4; ++rt) {
    short8v a[4];
#pragma unroll
    for (int kk = 0; kk < 4; ++kk) a[kk] = *(const short8v*)&At[rt * 16 + lrow][kk * 32 + kof];
    const int r0 = blk * 64 + rt * 16 + (l >> 4) * 4;
#pragma unroll
    for (int ct = 0; ct < 4; ++ct) {
      float4v acc = {0.f, 0.f, 0.f, 0.f};
#pragma unroll
      for (int kk = 0; kk < 4; ++kk)
        acc = __builtin_amdgcn_mfma_f32_16x16x32_bf16(a[kk], b[ct][kk], acc, 0, 0, 0);
      const int col = cbase + ct * 16;
      _Float16* O = (col < DF) ? fsh : fdh;
      const int c2 = (col < DF) ? col : col - DF;
#pragma unroll
      for (int r = 0; r < 4; ++r)
        if (r0 + r < NN) O[(r0 + r) * DF + c2] = (_Float16)acc[r];
    }
  }
}

// ---------------- partial readout body: out(+)= selected h @ R segments ----------------
// AFIRST: a in {0,1} (xb,h1b) and writes out with all biases; else a=2 (h2b), adds.
template <bool AFIRST>
__device__ __forceinline__ void readout_body(int blk, int tid,
                                             const unsigned short* __restrict__ h0b,
                                             const unsigned short* __restrict__ h1b,
                                             const unsigned short* __restrict__ h2b,
                                             const unsigned short* __restrict__ RT,
                                             const float* __restrict__ R0b,
                                             const float* __restrict__ R1b,
                                             const float* __restrict__ R2b,
                                             float* __restrict__ out) {
  const int w = tid >> 6, l = tid & 63;
  const int row0 = blk * 64 + w * 16;
  const int m = l & 15, ksub = (l >> 4) * 8;
  float4v acc = {0.f, 0.f, 0.f, 0.f};
  const unsigned short* hs[3] = {h0b, h1b, h2b};
  const int a0 = AFIRST ? 0 : 2, a1 = AFIRST ? 2 : 3;
#pragma unroll
  for (int a = a0; a < a1; ++a) {
    const unsigned short* __restrict__ H = hs[a];
#pragma unroll
    for (int kk = 0; kk < 4; ++kk) {
      const short8v av = *(const short8v*)(H + (size_t)(row0 + m) * DF + kk * 32 + ksub);
      const short8v bv = *(const short8v*)(RT + m * 384 + a * 128 + kk * 32 + ksub);
      acc = __builtin_amdgcn_mfma_f32_16x16x32_bf16(av, bv, acc, 0, 0, 0);
    }
  }
  const int r0 = row0 + (l >> 4) * 4;
  if (AFIRST) {
    const float rb = R0b[m] + R1b[m] + R2b[m];
#pragma unroll
    for (int r = 0; r < 4; ++r)
      if (r0 + r < NN) out[(r0 + r) * 16 + m] = acc[r] + rb;
  } else {
#pragma unroll
    for (int r = 0; r < 4; ++r)
      if (r0 + r < NN) out[(r0 + r) * 16 + m] += acc[r];
  }
}

// ---------------- stage1: proj L0 first, then GRID-STRIDED hist (XCD-ranged) ---------
__global__ __launch_bounds__(256) void stage1_kernel(
    const int* __restrict__ src, const int* __restrict__ dst, int* __restrict__ deg,
    unsigned short* __restrict__ ssrcB, const float* __restrict__ Xf,
    unsigned short* __restrict__ XbOut, const unsigned short* __restrict__ WT0,
    _Float16* __restrict__ fsh, _Float16* __restrict__ fdh) {
  __shared__ unsigned short At[64][136];
  const int b = blockIdx.x;
  const int tid = threadIdx.x;
  if (b >= PROJ_BLOCKS) {
    const int range = b & 7;                       // XCD id (blockIdx round-robin)
    const int rlo = range * 6250, rhi = rlo + 6250;
    const int hb = b - PROJ_BLOCKS;
    for (int c = hb >> 3; c < NCHUNK; c += HB_PER_RANGE) {
      const int e = c * 256 + tid;
      const int dn = dst[e];
      const int sv = src[e];           // coalesced read before divergence
      if (dn >= rlo && dn < rhi) {
        const int k = atomicAdd(&deg[dn], 1);
        if (k < BCAP) ssrcB[dn * BCAP + k] = (unsigned short)sv;
      }
    }
    return;
  }
  proj_body<true>(At, b, tid, nullptr, Xf, XbOut, WT0, fsh, fdh);
}

// ---------------- layer-1 projection + readout01 (both depend only on attn0) --------
// blocks [0, PROJ_BLOCKS): h1b @ WT1 -> fsh/fdh (MFMA).
// blocks [PROJ_BLOCKS, 2*PROJ_BLOCKS): out = xb@R0 + h1b@R1 + all biases.
__global__ __launch_bounds__(256) void projl1_rd01_kernel(
    const unsigned short* __restrict__ h1b, const unsigned short* __restrict__ WT,
    _Float16* __restrict__ fsh, _Float16* __restrict__ fdh,
    const unsigned short* __restrict__ xb, const unsigned short* __restrict__ RT,
    const float* __restrict__ R0b, const float* __restrict__ R1b,
    const float* __restrict__ R2b, float* __restrict__ out) {
  __shared__ unsigned short At[64][136];
  const int b = blockIdx.x;
  if (b < PROJ_BLOCKS) {
    proj_body<false>(At, b, threadIdx.x, h1b, nullptr, nullptr, WT, fsh, fdh);
  } else {
    readout_body<true>(b - PROJ_BLOCKS, threadIdx.x, xb, h1b, nullptr, RT,
                       R0b, R1b, R2b, out);
  }
}

// ---------------- readout2: out += h2b @ R2 ----------------
__global__ __launch_bounds__(256) void readout2_kernel(
    const unsigned short* __restrict__ h2b, const unsigned short* __restrict__ RT,
    float* __restrict__ out) {
  readout_body<false>(blockIdx.x, threadIdx.x, nullptr, nullptr, h2b, RT,
                      nullptr, nullptr, nullptr, out);
}

// ---------------- fused attention (fp16, depth-2 rotation-free pipeline, DPP reduce) --
// One wave per node, both heads. lane = eg(2b)|s16(4b): 16B fp16 load = 8 dims;
// 16 lanes cover 128 dims. Prefetch indices UNCLAMPED (worst over-read sb[79] ->
// neighbor buckets / pad after ssrcB; any u16 row index gathers inside the 25.6 MB
// fsh+fdh region; junk discarded by the tail guard). Logit reduce = 3 DPP adds.
__global__ __launch_bounds__(256) void csr_attention_kernel(
    const _Float16* __restrict__ fsh, const _Float16* __restrict__ fdh,
    const float* __restrict__ attn, const int* __restrict__ degv,
    const unsigned short* __restrict__ ssrcB, const float* __restrict__ bias,
    unsigned short* __restrict__ houtb) {
  const int node = (blockIdx.x * 256 + threadIdx.x) >> 6;
  const int lane = threadIdx.x & 63;
  const int eg = lane >> 4, s16 = lane & 15;
  const int deg = min(degv[node], BCAP);
  const unsigned short* __restrict__ sb = ssrcB + node * BCAP;
  const uint4* __restrict__ fsh4 = (const uint4*)fsh;

  half2v fdv[4], at[4];
  {
    const uint4 fq = ((const uint4*)fdh)[node * 16 + s16];
    fdv[0] = __builtin_bit_cast(half2v, fq.x);
    fdv[1] = __builtin_bit_cast(half2v, fq.y);
    fdv[2] = __builtin_bit_cast(half2v, fq.z);
    fdv[3] = __builtin_bit_cast(half2v, fq.w);
    const float4 a0 = ((const float4*)(attn + s16 * 8))[0];
    const float4 a1 = ((const float4*)(attn + s16 * 8))[1];
    const float l2e = 1.44269504f;
    at[0] = (half2v){(_Float16)(a0.x * l2e), (_Float16)(a0.y * l2e)};
    at[1] = (half2v){(_Float16)(a0.z * l2e), (_Float16)(a0.w * l2e)};
    at[2] = (half2v){(_Float16)(a1.x * l2e), (_Float16)(a1.y * l2e)};
    at[3] = (half2v){(_Float16)(a1.z * l2e), (_Float16)(a1.w * l2e)};
  }
  const half2v c02 = {(_Float16)0.2f, (_Float16)0.2f};

  float s = 0.f;
  half2v acc[4] = {{0, 0}, {0, 0}, {0, 0}, {0, 0}};
  const int nfull = deg >> 2;
  const int rem = deg & 3;

  auto consume = [&](const uint4 q) {
    half2v f[4];
    f[0] = __builtin_bit_cast(half2v, q.x);
    f[1] = __builtin_bit_cast(half2v, q.y);
    f[2] = __builtin_bit_cast(half2v, q.z);
    f[3] = __builtin_bit_cast(half2v, q.w);
    float v = 0.f;
#pragma unroll
    for (int k = 0; k < 4; ++k) {
      const half2v t = f[k] + fdv[k];                            // v_pk_add_f16
      const half2v lk = __builtin_elementwise_max(t, t * c02);   // pk_mul + pk_max
      v = __builtin_amdgcn_fdot2(lk, at[k], v, false);           // v_dot2_f32_f16
    }
    v = reduce8_dpp(v);                                          // 3 VALU-dpp adds
    const float p = exp2f(v);
    s += p;
    const _Float16 ph = (_Float16)p;
    const half2v p2 = {ph, ph};
#pragma unroll
    for (int k = 0; k < 4; ++k) acc[k] = p2 * f[k] + acc[k];     // v_pk_fma_f16
  };

  // primer: rows for iters 0,1 in flight; indices for iters 2,3 loaded
  int snA = (int)sb[eg];
  int snB = (int)sb[eg + 4];
  uint4 qA = fsh4[snA * 16 + s16];
  uint4 qB = fsh4[snB * 16 + s16];
  snA = (int)sb[eg + 8];
  snB = (int)sb[eg + 12];

  int base = eg + 16;
  const int npairs = nfull >> 1;
  for (int jj = 0; jj < npairs; ++jj) {
    consume(qA);
    qA = fsh4[snA * 16 + s16];                 // row for iter 2j+2
    snA = (int)sb[base];                       // index for iter 2j+4 (may over-read)
    consume(qB);
    qB = fsh4[snB * 16 + s16];                 // row for iter 2j+3
    snB = (int)sb[base + 4];                   // index for iter 2j+5 (may over-read)
    base += 8;
  }
  if (nfull & 1) {  // peel the odd full iteration; tail row then sits in qB
    consume(qA);
    qA = qB;
  }
  if (rem) {  // tail: qA holds row for edge eg + 4*nfull (junk-but-finite if eg >= rem)
    half2v f[4];
    f[0] = __builtin_bit_cast(half2v, qA.x);
    f[1] = __builtin_bit_cast(half2v, qA.y);
    f[2] = __builtin_bit_cast(half2v, qA.z);
    f[3] = __builtin_bit_cast(half2v, qA.w);
    float v = 0.f;
#pragma unroll
    for (int k = 0; k < 4; ++k) {
      const half2v t = f[k] + fdv[k];
      const half2v lk = __builtin_elementwise_max(t, t * c02);
      v = __builtin_amdgcn_fdot2(lk, at[k], v, false);
    }
    v = reduce8_dpp(v);
    const float p = (eg < rem) ? exp2f(v) : 0.f;                 // guard zeroes junk
    s += p;
    const _Float16 ph = (_Float16)p;
    const half2v p2 = {ph, ph};
#pragma unroll
    for (int k = 0; k < 4; ++k) acc[k] = p2 * f[k] + acc[k];
  }

  // merge the 4 edge groups (one 32-bit shfl moves 2 dims)
#pragma unroll
  for (int dist = 16; dist <= 32; dist <<= 1) {
    s += __shfl_xor(s, dist);
#pragma unroll
    for (int k = 0; k < 4; ++k) {
      const float of = __shfl_xor(__builtin_bit_cast(float, acc[k]), dist);
      acc[k] = acc[k] + __builtin_bit_cast(half2v, of);
    }
  }

  if (lane < 16) {
    const float rs = (deg > 0) ? 1.0f / s : 0.0f;
    const float4 b0 = ((const float4*)(bias + s16 * 8))[0];
    const float4 b1 = ((const float4*)(bias + s16 * 8))[1];
    const float bb[8] = {b0.x, b0.y, b0.z, b0.w, b1.x, b1.y, b1.z, b1.w};
    float ob[8];
#pragma unroll
    for (int k = 0; k < 4; ++k) {
      ob[2 * k]     = leaky(fmaf((float)acc[k].x, rs, bb[2 * k]));
      ob[2 * k + 1] = leaky(fmaf((float)acc[k].y, rs, bb[2 * k + 1]));
    }
    uint4 w;
    w.x = rne_bf16(ob[0]) | ((unsigned)rne_bf16(ob[1]) << 16);
    w.y = rne_bf16(ob[2]) | ((unsigned)rne_bf16(ob[3]) << 16);
    w.z = rne_bf16(ob[4]) | ((unsigned)rne_bf16(ob[5]) << 16);
    w.w = rne_bf16(ob[6]) | ((unsigned)rne_bf16(ob[7]) << 16);
    ((uint4*)houtb)[node * 16 + s16] = w;
  }
}

extern "C" void kernel_launch(void* const* d_in, const int* in_sizes, int n_in,
                              void* d_out, int out_size, void* d_ws, size_t ws_size,
                              hipStream_t stream) {
  const float* x     = (const float*)d_in[0];
  const int*   src   = (const int*)d_in[1];
  const int*   dst   = (const int*)d_in[2];
  const float* Wsrc0 = (const float*)d_in[3];
  const float* Wdst0 = (const float*)d_in[4];
  const float* attn0 = (const float*)d_in[5];
  const float* bias0 = (const float*)d_in[6];
  const float* Wsrc1 = (const float*)d_in[7];
  const float* Wdst1 = (const float*)d_in[8];
  const float* attn1 = (const float*)d_in[9];
  const float* bias1 = (const float*)d_in[10];
  const float* R0W   = (const float*)d_in[11];
  const float* R0b   = (const float*)d_in[12];
  const float* R1W   = (const float*)d_in[13];
  const float* R1b   = (const float*)d_in[14];
  const float* R2W   = (const float*)d_in[15];
  const float* R2b   = (const float*)d_in[16];
  float* out = (float*)d_out;

  // workspace: xb | h1b | h2b (NNP rows bf16) | fsh | fdh (NN rows fp16)
  //            | WT0 | WT1 | RT (bf16) | deg (int) | ssrcB (+512 pad, u16)   ~= 71 MB
  unsigned short* xb  = (unsigned short*)d_ws;
  unsigned short* h1b = xb + (size_t)NNP * DF;
  unsigned short* h2b = h1b + (size_t)NNP * DF;
  _Float16* fsh = (_Float16*)(h2b + (size_t)NNP * DF);
  _Float16* fdh = fsh + (size_t)NN * DF;
  unsigned short* WT0 = (unsigned short*)(fdh + (size_t)NN * DF);
  unsigned short* WT1 = WT0 + 256 * DF;
  unsigned short* RT  = WT1 + 256 * DF;
  int* deg = (int*)(RT + 16 * 384);
  unsigned short* ssrcB = (unsigned short*)(deg + NN);
  // (ssrcB spans NN*BCAP + 512-entry slack for unclamped prefetch over-reads)

  // ---- launch 1: zero deg + all weight casts ----
  prep_kernel<<<476, 256, 0, stream>>>(deg, Wsrc0, Wdst0, Wsrc1, Wdst1, WT0, WT1,
                                       R0W, R1W, R2W, RT);

  // ---- launch 2: proj L0 (blocks 0..781) + grid-strided hist (XCD-ranged) ----
  stage1_kernel<<<PROJ_BLOCKS + HF_BLOCKS, 256, 0, stream>>>(
      src, dst, deg, ssrcB, x, xb, WT0, fsh, fdh);

  // ---- layer 0 attention ----
  csr_attention_kernel<<<(NN * 64) / 256, 256, 0, stream>>>(fsh, fdh, attn0, deg, ssrcB, bias0, h1b);

  // ---- layer 1 projection + readout01 (out = xb@R0 + h1b@R1 + biases) ----
  projl1_rd01_kernel<<<2 * PROJ_BLOCKS, 256, 0, stream>>>(
      h1b, WT1, fsh, fdh, xb, RT, R0b, R1b, R2b, out);

  // ---- layer 1 attention ----
  csr_attention_kernel<<<(NN * 64) / 256, 256, 0, stream>>>(fsh, fdh, attn1, deg, ssrcB, bias1, h2b);

  // ---- readout2: out += h2b @ R2 ----
  readout2_kernel<<<NNP / 64, 256, 0, stream>>>(h2b, RT, out);
}

// Round 19
// 144.354 us; speedup vs baseline: 1.0483x; 1.0202x over previous
//
#include <hip/hip_runtime.h>

#define NN 50000
#define NNP 50048  // padded row count (multiple of 64) for MFMA kernels
#define NE 800000
#define DF 128     // H * D_HID == D_IN
#define BCAP 64    // per-node edge bucket capacity (deg ~ Poisson(16): P(>64) ~ 0)
#define NCHUNK (NE / 256)              // 3125 edge chunks of 256
#define HB_PER_RANGE 256               // hist blocks per dst-range (13 iters/block)
#define HF_BLOCKS (HB_PER_RANGE * 8)   // 2048 grid-strided hist blocks
#define PROJ_BLOCKS ((NN + 63) / 64)   // 782 (64-row tiles)

typedef __attribute__((ext_vector_type(8))) short short8v;    // 8 bf16 (4 VGPRs)
typedef __attribute__((ext_vector_type(4))) float float4v;    // MFMA acc
typedef __attribute__((ext_vector_type(2))) _Float16 half2v;  // packed fp16 pair

__device__ __forceinline__ float leaky(float t) { return fmaxf(t, 0.2f * t); }

__device__ __forceinline__ unsigned short rne_bf16(float x) {
  unsigned u = __float_as_uint(x);
  u = (u + 0x7fffu + ((u >> 16) & 1u)) >> 16;
  return (unsigned short)u;
}

// f32 add over DPP lane-permute (full-rate VALU; avoids ds_bpermute latency)
template <int CTRL>
__device__ __forceinline__ float dpp_add(float v) {
  const int i = __builtin_bit_cast(int, v);
  const int p = __builtin_amdgcn_update_dpp(0, i, CTRL, 0xF, 0xF, true);
  return v + __builtin_bit_cast(float, p);
}
// sum over 8 contiguous lanes: xor1 (0xB1), xor2 (0x4E), row_half_mirror (0x141)
__device__ __forceinline__ float reduce8_dpp(float v) {
  v = dpp_add<0xB1>(v);
  v = dpp_add<0x4E>(v);
  v = dpp_add<0x141>(v);
  return v;
}
// sum over 16 contiguous lanes (one DPP row): reduce8 + row_mirror (0x140)
__device__ __forceinline__ float reduce16_dpp(float v) {
  v = reduce8_dpp(v);
  v = dpp_add<0x140>(v);
  return v;
}

// ---------------- prep: zero deg + ALL weight casts (WT0 must precede proj L0) -------
// blocks [0,196) zero deg; [196,452) WT casts; [452,476) RT casts
__global__ void prep_kernel(int* __restrict__ deg,
                            const float* __restrict__ Ws0, const float* __restrict__ Wd0,
                            const float* __restrict__ Ws1, const float* __restrict__ Wd1,
                            unsigned short* __restrict__ WT0, unsigned short* __restrict__ WT1,
                            const float* __restrict__ R0W, const float* __restrict__ R1W,
                            const float* __restrict__ R2W, unsigned short* __restrict__ RT) {
  const int b = blockIdx.x;
  const int tid = threadIdx.x;
  if (b < 196) {
    const int i = b * 256 + tid;
    if (i < NN) deg[i] = 0;
  } else if (b < 452) {                // WT[l][256][128]: row c<128 -> Wsrc col c, else Wdst
    const int idx = (b - 196) * 256 + tid;   // 0..65535
    const int l = idx >> 15;
    const int r = (idx >> 7) & 255;
    const int k = idx & 127;
    const float* Ws = l ? Ws1 : Ws0;
    const float* Wd = l ? Wd1 : Wd0;
    const float v = (r < 128) ? Ws[k * DF + r] : Wd[k * DF + (r - 128)];
    (l ? WT1 : WT0)[r * DF + k] = rne_bf16(v);
  } else {                             // RT[16][384]
    const int idx = (b - 452) * 256 + tid;   // 0..6143
    const int c = idx / 384, k = idx - c * 384;
    const float* Rw = (k < 128) ? R0W : (k < 256) ? R1W : R2W;
    RT[c * 384 + k] = rne_bf16(Rw[(k & 127) * 16 + c]);
  }
}

// ---------------- shared MFMA projection body, 64-row tiles ----------------
// L0: f32 input + xb write-through. 4 waves x 64 cols each; 4 row-tiles of 16.
template <bool L0>
__device__ __forceinline__ void proj_body(unsigned short (*At)[136], int blk, int tid,
                                          const unsigned short* __restrict__ Ab,
                                          const float* __restrict__ Xf,
                                          unsigned short* __restrict__ XbOut,
                                          const unsigned short* __restrict__ WT,
                                          _Float16* __restrict__ fsh,
                                          _Float16* __restrict__ fdh) {
  const int w = tid >> 6, l = tid & 63;

#pragma unroll
  for (int i = 0; i < 4; ++i) {
    const int flat = i * 256 + tid;
    const int r = flat >> 4, c16 = flat & 15;
    const int row = blk * 64 + r;
    uint4 v = make_uint4(0, 0, 0, 0);
    if (L0) {
      if (row < NN) {
        const float4 a = ((const float4*)Xf)[row * 32 + c16 * 2];
        const float4 bq = ((const float4*)Xf)[row * 32 + c16 * 2 + 1];
        v.x = rne_bf16(a.x) | ((unsigned)rne_bf16(a.y) << 16);
        v.y = rne_bf16(a.z) | ((unsigned)rne_bf16(a.w) << 16);
        v.z = rne_bf16(bq.x) | ((unsigned)rne_bf16(bq.y) << 16);
        v.w = rne_bf16(bq.z) | ((unsigned)rne_bf16(bq.w) << 16);
        ((uint4*)XbOut)[row * 16 + c16] = v;   // write-through for readout h0
      }
    } else {
      if (row < NN) v = ((const uint4*)Ab)[row * 16 + c16];
    }
    *(uint4*)&At[r][c16 * 8] = v;
  }

  const int kof = (l >> 4) * 8;
  const int cbase = w * 64 + (l & 15);
  short8v b[4][4];
#pragma unroll
  for (int ct = 0; ct < 4; ++ct)
#pragma unroll
    for (int kk = 0; kk < 4; ++kk)
      b[ct][kk] = *(const short8v*)(WT + (cbase + ct * 16) * DF + kk * 32 + kof);
  __syncthreads();

  const int lrow = l & 15;
#pragma unroll
  for (int rt = 0; rt < 4; ++rt) {
    short8v a[4];
#pragma unroll
    for (int kk = 0; kk < 4; ++kk) a[kk] = *(const short8v*)&At[rt * 16 + lrow][kk * 32 + kof];
    const int r0 = blk * 64 + rt * 16 + (l >> 4) * 4;
#pragma unroll
    for (int ct = 0; ct < 4; ++ct) {
      float4v acc = {0.f, 0.f, 0.f, 0.f};
#pragma unroll
      for (int kk = 0; kk < 4; ++kk)
        acc = __builtin_amdgcn_mfma_f32_16x16x32_bf16(a[kk], b[ct][kk], acc, 0, 0, 0);
      const int col = cbase + ct * 16;
      _Float16* O = (col < DF) ? fsh : fdh;
      const int c2 = (col < DF) ? col : col - DF;
#pragma unroll
      for (int r = 0; r < 4; ++r)
        if (r0 + r < NN) O[(r0 + r) * DF + c2] = (_Float16)acc[r];
    }
  }
}

// ---------------- readout01 body: out = xb@R0 + h1b@R1 + all biases ----------------
__device__ __forceinline__ void readout01_body(int blk, int tid,
                                               const unsigned short* __restrict__ h0b,
                                               const unsigned short* __restrict__ h1b,
                                               const unsigned short* __restrict__ RT,
                                               const float* __restrict__ R0b,
                                               const float* __restrict__ R1b,
                                               const float* __restrict__ R2b,
                                               float* __restrict__ out) {
  const int w = tid >> 6, l = tid & 63;
  const int row0 = blk * 64 + w * 16;
  const int m = l & 15, ksub = (l >> 4) * 8;
  float4v acc = {0.f, 0.f, 0.f, 0.f};
  const unsigned short* hs[2] = {h0b, h1b};
#pragma unroll
  for (int a = 0; a < 2; ++a) {
    const unsigned short* __restrict__ H = hs[a];
#pragma unroll
    for (int kk = 0; kk < 4; ++kk) {
      const short8v av = *(const short8v*)(H + (size_t)(row0 + m) * DF + kk * 32 + ksub);
      const short8v bv = *(const short8v*)(RT + m * 384 + a * 128 + kk * 32 + ksub);
      acc = __builtin_amdgcn_mfma_f32_16x16x32_bf16(av, bv, acc, 0, 0, 0);
    }
  }
  const int r0 = row0 + (l >> 4) * 4;
  const float rb = R0b[m] + R1b[m] + R2b[m];
#pragma unroll
  for (int r = 0; r < 4; ++r)
    if (r0 + r < NN) out[(r0 + r) * 16 + m] = acc[r] + rb;
}

// ---------------- stage1: proj L0 first, then GRID-STRIDED hist (XCD-ranged) ---------
__global__ __launch_bounds__(256) void stage1_kernel(
    const int* __restrict__ src, const int* __restrict__ dst, int* __restrict__ deg,
    unsigned short* __restrict__ ssrcB, const float* __restrict__ Xf,
    unsigned short* __restrict__ XbOut, const unsigned short* __restrict__ WT0,
    _Float16* __restrict__ fsh, _Float16* __restrict__ fdh) {
  __shared__ unsigned short At[64][136];
  const int b = blockIdx.x;
  const int tid = threadIdx.x;
  if (b >= PROJ_BLOCKS) {
    const int range = b & 7;                       // XCD id (blockIdx round-robin)
    const int rlo = range * 6250, rhi = rlo + 6250;
    const int hb = b - PROJ_BLOCKS;
    for (int c = hb >> 3; c < NCHUNK; c += HB_PER_RANGE) {
      const int e = c * 256 + tid;
      const int dn = dst[e];
      const int sv = src[e];           // coalesced read before divergence
      if (dn >= rlo && dn < rhi) {
        const int k = atomicAdd(&deg[dn], 1);
        if (k < BCAP) ssrcB[dn * BCAP + k] = (unsigned short)sv;
      }
    }
    return;
  }
  proj_body<true>(At, b, tid, nullptr, Xf, XbOut, WT0, fsh, fdh);
}

// ---------------- layer-1 projection + readout01 (both depend only on attn0) --------
__global__ __launch_bounds__(256) void projl1_rd01_kernel(
    const unsigned short* __restrict__ h1b, const unsigned short* __restrict__ WT,
    _Float16* __restrict__ fsh, _Float16* __restrict__ fdh,
    const unsigned short* __restrict__ xb, const unsigned short* __restrict__ RT,
    const float* __restrict__ R0b, const float* __restrict__ R1b,
    const float* __restrict__ R2b, float* __restrict__ out) {
  __shared__ unsigned short At[64][136];
  const int b = blockIdx.x;
  if (b < PROJ_BLOCKS) {
    proj_body<false>(At, b, threadIdx.x, h1b, nullptr, nullptr, WT, fsh, fdh);
  } else {
    readout01_body(b - PROJ_BLOCKS, threadIdx.x, xb, h1b, RT, R0b, R1b, R2b, out);
  }
}

// ---------------- fused attention (fp16, depth-2 pipeline, DPP reduce) ----------------
// One wave per node, both heads. lane = eg(2b)|s16(4b): 16B fp16 load = 8 dims.
// FUSED_RD (layer 1): instead of writing the bf16 h-row, fold out += h2@R2 into the
// epilogue -- each lane computes 4 output cols (c=eg*4+cc) over its 8 dims (2048 FMA
// total across the wave, zero duplication), reduce16_dpp per col, one float4 RMW per
// edge-group. h2b never materializes.
template <bool FUSED_RD>
__global__ __launch_bounds__(256) void csr_attention_kernel(
    const _Float16* __restrict__ fsh, const _Float16* __restrict__ fdh,
    const float* __restrict__ attn, const int* __restrict__ degv,
    const unsigned short* __restrict__ ssrcB, const float* __restrict__ bias,
    unsigned short* __restrict__ houtb, const unsigned short* __restrict__ RT,
    float* __restrict__ out) {
  const int node = (blockIdx.x * 256 + threadIdx.x) >> 6;
  const int lane = threadIdx.x & 63;
  const int eg = lane >> 4, s16 = lane & 15;
  const int deg = min(degv[node], BCAP);
  const unsigned short* __restrict__ sb = ssrcB + node * BCAP;
  const uint4* __restrict__ fsh4 = (const uint4*)fsh;

  half2v fdv[4], at[4];
  {
    const uint4 fq = ((const uint4*)fdh)[node * 16 + s16];
    fdv[0] = __builtin_bit_cast(half2v, fq.x);
    fdv[1] = __builtin_bit_cast(half2v, fq.y);
    fdv[2] = __builtin_bit_cast(half2v, fq.z);
    fdv[3] = __builtin_bit_cast(half2v, fq.w);
    const float4 a0 = ((const float4*)(attn + s16 * 8))[0];
    const float4 a1 = ((const float4*)(attn + s16 * 8))[1];
    const float l2e = 1.44269504f;
    at[0] = (half2v){(_Float16)(a0.x * l2e), (_Float16)(a0.y * l2e)};
    at[1] = (half2v){(_Float16)(a0.z * l2e), (_Float16)(a0.w * l2e)};
    at[2] = (half2v){(_Float16)(a1.x * l2e), (_Float16)(a1.y * l2e)};
    at[3] = (half2v){(_Float16)(a1.z * l2e), (_Float16)(a1.w * l2e)};
  }
  const half2v c02 = {(_Float16)0.2f, (_Float16)0.2f};

  float s = 0.f;
  half2v acc[4] = {{0, 0}, {0, 0}, {0, 0}, {0, 0}};
  const int nfull = deg >> 2;
  const int rem = deg & 3;

  auto consume = [&](const uint4 q) {
    half2v f[4];
    f[0] = __builtin_bit_cast(half2v, q.x);
    f[1] = __builtin_bit_cast(half2v, q.y);
    f[2] = __builtin_bit_cast(half2v, q.z);
    f[3] = __builtin_bit_cast(half2v, q.w);
    float v = 0.f;
#pragma unroll
    for (int k = 0; k < 4; ++k) {
      const half2v t = f[k] + fdv[k];                            // v_pk_add_f16
      const half2v lk = __builtin_elementwise_max(t, t * c02);   // pk_mul + pk_max
      v = __builtin_amdgcn_fdot2(lk, at[k], v, false);           // v_dot2_f32_f16
    }
    v = reduce8_dpp(v);                                          // 3 VALU-dpp adds
    const float p = exp2f(v);
    s += p;
    const _Float16 ph = (_Float16)p;
    const half2v p2 = {ph, ph};
#pragma unroll
    for (int k = 0; k < 4; ++k) acc[k] = p2 * f[k] + acc[k];     // v_pk_fma_f16
  };

  // primer: rows for iters 0,1 in flight; indices for iters 2,3 loaded
  int snA = (int)sb[eg];
  int snB = (int)sb[eg + 4];
  uint4 qA = fsh4[snA * 16 + s16];
  uint4 qB = fsh4[snB * 16 + s16];
  snA = (int)sb[eg + 8];
  snB = (int)sb[eg + 12];

  int base = eg + 16;
  const int npairs = nfull >> 1;
  for (int jj = 0; jj < npairs; ++jj) {
    consume(qA);
    qA = fsh4[snA * 16 + s16];                 // row for iter 2j+2
    snA = (int)sb[base];                       // index for iter 2j+4 (may over-read)
    consume(qB);
    qB = fsh4[snB * 16 + s16];                 // row for iter 2j+3
    snB = (int)sb[base + 4];                   // index for iter 2j+5 (may over-read)
    base += 8;
  }
  if (nfull & 1) {  // peel the odd full iteration; tail row then sits in qB
    consume(qA);
    qA = qB;
  }
  if (rem) {  // tail: qA holds row for edge eg + 4*nfull (junk-but-finite if eg >= rem)
    half2v f[4];
    f[0] = __builtin_bit_cast(half2v, qA.x);
    f[1] = __builtin_bit_cast(half2v, qA.y);
    f[2] = __builtin_bit_cast(half2v, qA.z);
    f[3] = __builtin_bit_cast(half2v, qA.w);
    float v = 0.f;
#pragma unroll
    for (int k = 0; k < 4; ++k) {
      const half2v t = f[k] + fdv[k];
      const half2v lk = __builtin_elementwise_max(t, t * c02);
      v = __builtin_amdgcn_fdot2(lk, at[k], v, false);
    }
    v = reduce8_dpp(v);
    const float p = (eg < rem) ? exp2f(v) : 0.f;                 // guard zeroes junk
    s += p;
    const _Float16 ph = (_Float16)p;
    const half2v p2 = {ph, ph};
#pragma unroll
    for (int k = 0; k < 4; ++k) acc[k] = p2 * f[k] + acc[k];
  }

  // merge the 4 edge groups (one 32-bit shfl moves 2 dims)
#pragma unroll
  for (int dist = 16; dist <= 32; dist <<= 1) {
    s += __shfl_xor(s, dist);
#pragma unroll
    for (int k = 0; k < 4; ++k) {
      const float of = __shfl_xor(__builtin_bit_cast(float, acc[k]), dist);
      acc[k] = acc[k] + __builtin_bit_cast(half2v, of);
    }
  }

  // epilogue: all lanes hold the merged row slice for dims d = s16*8 + j
  const float rs = (deg > 0) ? 1.0f / s : 0.0f;
  const float4 b0 = ((const float4*)(bias + s16 * 8))[0];
  const float4 b1 = ((const float4*)(bias + s16 * 8))[1];
  const float bb[8] = {b0.x, b0.y, b0.z, b0.w, b1.x, b1.y, b1.z, b1.w};
  float ob[8];
#pragma unroll
  for (int k = 0; k < 4; ++k) {
    ob[2 * k]     = leaky(fmaf((float)acc[k].x, rs, bb[2 * k]));
    ob[2 * k + 1] = leaky(fmaf((float)acc[k].y, rs, bb[2 * k + 1]));
  }

  if constexpr (!FUSED_RD) {
    if (lane < 16) {
      uint4 w;
      w.x = rne_bf16(ob[0]) | ((unsigned)rne_bf16(ob[1]) << 16);
      w.y = rne_bf16(ob[2]) | ((unsigned)rne_bf16(ob[3]) << 16);
      w.z = rne_bf16(ob[4]) | ((unsigned)rne_bf16(ob[5]) << 16);
      w.w = rne_bf16(ob[6]) | ((unsigned)rne_bf16(ob[7]) << 16);
      ((uint4*)houtb)[node * 16 + s16] = w;
    }
  } else {
    // out[node][c] += sum_d ob_row[d] * R2[d][c]; lane covers c = eg*4+cc, d = s16*8+j
    float rsum[4];
#pragma unroll
    for (int cc = 0; cc < 4; ++cc) {
      const short8v rv = *(const short8v*)(RT + (eg * 4 + cc) * 384 + 256 + s16 * 8);
      float t = 0.f;
#pragma unroll
      for (int j = 0; j < 8; ++j)
        t = fmaf(__uint_as_float(((unsigned)(unsigned short)rv[j]) << 16), ob[j], t);
      rsum[cc] = reduce16_dpp(t);
    }
    if (s16 == 0) {
      float4* o4 = (float4*)(out + node * 16 + eg * 4);
      float4 cur = *o4;
      cur.x += rsum[0];
      cur.y += rsum[1];
      cur.z += rsum[2];
      cur.w += rsum[3];
      *o4 = cur;
    }
  }
}

extern "C" void kernel_launch(void* const* d_in, const int* in_sizes, int n_in,
                              void* d_out, int out_size, void* d_ws, size_t ws_size,
                              hipStream_t stream) {
  const float* x     = (const float*)d_in[0];
  const int*   src   = (const int*)d_in[1];
  const int*   dst   = (const int*)d_in[2];
  const float* Wsrc0 = (const float*)d_in[3];
  const float* Wdst0 = (const float*)d_in[4];
  const float* attn0 = (const float*)d_in[5];
  const float* bias0 = (const float*)d_in[6];
  const float* Wsrc1 = (const float*)d_in[7];
  const float* Wdst1 = (const float*)d_in[8];
  const float* attn1 = (const float*)d_in[9];
  const float* bias1 = (const float*)d_in[10];
  const float* R0W   = (const float*)d_in[11];
  const float* R0b   = (const float*)d_in[12];
  const float* R1W   = (const float*)d_in[13];
  const float* R1b   = (const float*)d_in[14];
  const float* R2W   = (const float*)d_in[15];
  const float* R2b   = (const float*)d_in[16];
  float* out = (float*)d_out;

  // workspace: xb | h1b (NNP rows bf16) | fsh | fdh (NN rows fp16)
  //            | WT0 | WT1 | RT (bf16) | deg (int) | ssrcB (+512 pad, u16)   ~= 58 MB
  unsigned short* xb  = (unsigned short*)d_ws;
  unsigned short* h1b = xb + (size_t)NNP * DF;
  _Float16* fsh = (_Float16*)(h1b + (size_t)NNP * DF);
  _Float16* fdh = fsh + (size_t)NN * DF;
  unsigned short* WT0 = (unsigned short*)(fdh + (size_t)NN * DF);
  unsigned short* WT1 = WT0 + 256 * DF;
  unsigned short* RT  = WT1 + 256 * DF;
  int* deg = (int*)(RT + 16 * 384);
  unsigned short* ssrcB = (unsigned short*)(deg + NN);
  // (ssrcB spans NN*BCAP + 512-entry slack for unclamped prefetch over-reads)

  // ---- launch 1: zero deg + all weight casts ----
  prep_kernel<<<476, 256, 0, stream>>>(deg, Wsrc0, Wdst0, Wsrc1, Wdst1, WT0, WT1,
                                       R0W, R1W, R2W, RT);

  // ---- launch 2: proj L0 (blocks 0..781) + grid-strided hist (XCD-ranged) ----
  stage1_kernel<<<PROJ_BLOCKS + HF_BLOCKS, 256, 0, stream>>>(
      src, dst, deg, ssrcB, x, xb, WT0, fsh, fdh);

  // ---- launch 3: layer 0 attention -> h1b ----
  csr_attention_kernel<false><<<(NN * 64) / 256, 256, 0, stream>>>(
      fsh, fdh, attn0, deg, ssrcB, bias0, h1b, nullptr, nullptr);

  // ---- launch 4: layer 1 projection + readout01 (out = xb@R0 + h1b@R1 + biases) ----
  projl1_rd01_kernel<<<2 * PROJ_BLOCKS, 256, 0, stream>>>(
      h1b, WT1, fsh, fdh, xb, RT, R0b, R1b, R2b, out);

  // ---- launch 5: layer 1 attention with fused out += h2@R2 (h2 never materialized) --
  csr_attention_kernel<true><<<(NN * 64) / 256, 256, 0, stream>>>(
      fsh, fdh, attn1, deg, ssrcB, bias1, nullptr, RT, out);
}

// Round 20
// 143.164 us; speedup vs baseline: 1.0570x; 1.0083x over previous
//
#include <hip/hip_runtime.h>

#define NN 50000
#define NNP 50048  // padded row count (multiple of 64) for MFMA kernels
#define NE 800000
#define DF 128     // H * D_HID == D_IN
#define BCAP 64    // per-node edge bucket capacity (deg ~ Poisson(16): P(>64) ~ 0)
#define NCHUNK (NE / 256)              // 3125 edge chunks of 256
#define HB_PER_RANGE 256               // hist blocks per dst-range (13 iters/block)
#define HF_BLOCKS (HB_PER_RANGE * 8)   // 2048 grid-strided hist blocks
#define PROJ_BLOCKS ((NN + 63) / 64)   // 782 (64-row tiles)

typedef __attribute__((ext_vector_type(8))) short short8v;    // 8 bf16 (4 VGPRs)
typedef __attribute__((ext_vector_type(4))) float float4v;    // MFMA acc
typedef __attribute__((ext_vector_type(2))) _Float16 half2v;  // packed fp16 pair

__device__ __forceinline__ float leaky(float t) { return fmaxf(t, 0.2f * t); }

__device__ __forceinline__ unsigned short rne_bf16(float x) {
  unsigned u = __float_as_uint(x);
  u = (u + 0x7fffu + ((u >> 16) & 1u)) >> 16;
  return (unsigned short)u;
}

// f32 add over DPP lane-permute (full-rate VALU; avoids ds_bpermute latency)
template <int CTRL>
__device__ __forceinline__ float dpp_add(float v) {
  const int i = __builtin_bit_cast(int, v);
  const int p = __builtin_amdgcn_update_dpp(0, i, CTRL, 0xF, 0xF, true);
  return v + __builtin_bit_cast(float, p);
}
// sum over 8 contiguous lanes: xor1 (0xB1), xor2 (0x4E), row_half_mirror (0x141)
__device__ __forceinline__ float reduce8_dpp(float v) {
  v = dpp_add<0xB1>(v);
  v = dpp_add<0x4E>(v);
  v = dpp_add<0x141>(v);
  return v;
}
// sum over 16 contiguous lanes (one DPP row): reduce8 + row_mirror (0x140)
__device__ __forceinline__ float reduce16_dpp(float v) {
  v = reduce8_dpp(v);
  v = dpp_add<0x140>(v);
  return v;
}

// ---------------- prep: zero deg + weight casts + edge pack ----------------
// blocks [0,196) zero deg; [196,452) WT casts; [452,476) RT casts;
// [476, 476+NCHUNK): pack epk[e] = dst | (src<<16)  (both < 2^16)
__global__ void prep_kernel(int* __restrict__ deg,
                            const float* __restrict__ Ws0, const float* __restrict__ Wd0,
                            const float* __restrict__ Ws1, const float* __restrict__ Wd1,
                            unsigned short* __restrict__ WT0, unsigned short* __restrict__ WT1,
                            const float* __restrict__ R0W, const float* __restrict__ R1W,
                            const float* __restrict__ R2W, unsigned short* __restrict__ RT,
                            const int* __restrict__ src, const int* __restrict__ dst,
                            unsigned* __restrict__ epk) {
  const int b = blockIdx.x;
  const int tid = threadIdx.x;
  if (b < 196) {
    const int i = b * 256 + tid;
    if (i < NN) deg[i] = 0;
  } else if (b < 452) {                // WT[l][256][128]: row c<128 -> Wsrc col c, else Wdst
    const int idx = (b - 196) * 256 + tid;   // 0..65535
    const int l = idx >> 15;
    const int r = (idx >> 7) & 255;
    const int k = idx & 127;
    const float* Ws = l ? Ws1 : Ws0;
    const float* Wd = l ? Wd1 : Wd0;
    const float v = (r < 128) ? Ws[k * DF + r] : Wd[k * DF + (r - 128)];
    (l ? WT1 : WT0)[r * DF + k] = rne_bf16(v);
  } else if (b < 476) {                // RT[16][384]
    const int idx = (b - 452) * 256 + tid;   // 0..6143
    const int c = idx / 384, k = idx - c * 384;
    const float* Rw = (k < 128) ? R0W : (k < 256) ? R1W : R2W;
    RT[c * 384 + k] = rne_bf16(Rw[(k & 127) * 16 + c]);
  } else {                             // edge pack
    const int e = (b - 476) * 256 + tid;
    epk[e] = (unsigned)dst[e] | ((unsigned)src[e] << 16);
  }
}

// ---------------- shared MFMA projection body, 64-row tiles ----------------
// L0: f32 input + xb write-through. 4 waves x 64 cols each; 4 row-tiles of 16.
template <bool L0>
__device__ __forceinline__ void proj_body(unsigned short (*At)[136], int blk, int tid,
                                          const unsigned short* __restrict__ Ab,
                                          const float* __restrict__ Xf,
                                          unsigned short* __restrict__ XbOut,
                                          const unsigned short* __restrict__ WT,
                                          _Float16* __restrict__ fsh,
                                          _Float16* __restrict__ fdh) {
  const int w = tid >> 6, l = tid & 63;

#pragma unroll
  for (int i = 0; i < 4; ++i) {
    const int flat = i * 256 + tid;
    const int r = flat >> 4, c16 = flat & 15;
    const int row = blk * 64 + r;
    uint4 v = make_uint4(0, 0, 0, 0);
    if (L0) {
      if (row < NN) {
        const float4 a = ((const float4*)Xf)[row * 32 + c16 * 2];
        const float4 bq = ((const float4*)Xf)[row * 32 + c16 * 2 + 1];
        v.x = rne_bf16(a.x) | ((unsigned)rne_bf16(a.y) << 16);
        v.y = rne_bf16(a.z) | ((unsigned)rne_bf16(a.w) << 16);
        v.z = rne_bf16(bq.x) | ((unsigned)rne_bf16(bq.y) << 16);
        v.w = rne_bf16(bq.z) | ((unsigned)rne_bf16(bq.w) << 16);
        ((uint4*)XbOut)[row * 16 + c16] = v;   // write-through for readout h0
      }
    } else {
      if (row < NN) v = ((const uint4*)Ab)[row * 16 + c16];
    }
    *(uint4*)&At[r][c16 * 8] = v;
  }

  const int kof = (l >> 4) * 8;
  const int cbase = w * 64 + (l & 15);
  short8v b[4][4];
#pragma unroll
  for (int ct = 0; ct < 4; ++ct)
#pragma unroll
    for (int kk = 0; kk < 4; ++kk)
      b[ct][kk] = *(const short8v*)(WT + (cbase + ct * 16) * DF + kk * 32 + kof);
  __syncthreads();

  const int lrow = l & 15;
#pragma unroll
  for (int rt = 0; rt < 4; ++rt) {
    short8v a[4];
#pragma unroll
    for (int kk = 0; kk < 4; ++kk) a[kk] = *(const short8v*)&At[rt * 16 + lrow][kk * 32 + kof];
    const int r0 = blk * 64 + rt * 16 + (l >> 4) * 4;
#pragma unroll
    for (int ct = 0; ct < 4; ++ct) {
      float4v acc = {0.f, 0.f, 0.f, 0.f};
#pragma unroll
      for (int kk = 0; kk < 4; ++kk)
        acc = __builtin_amdgcn_mfma_f32_16x16x32_bf16(a[kk], b[ct][kk], acc, 0, 0, 0);
      const int col = cbase + ct * 16;
      _Float16* O = (col < DF) ? fsh : fdh;
      const int c2 = (col < DF) ? col : col - DF;
#pragma unroll
      for (int r = 0; r < 4; ++r)
        if (r0 + r < NN) O[(r0 + r) * DF + c2] = (_Float16)acc[r];
    }
  }
}

// ---------------- readout01 body: out = xb@R0 + h1b@R1 + all biases ----------------
__device__ __forceinline__ void readout01_body(int blk, int tid,
                                               const unsigned short* __restrict__ h0b,
                                               const unsigned short* __restrict__ h1b,
                                               const unsigned short* __restrict__ RT,
                                               const float* __restrict__ R0b,
                                               const float* __restrict__ R1b,
                                               const float* __restrict__ R2b,
                                               float* __restrict__ out) {
  const int w = tid >> 6, l = tid & 63;
  const int row0 = blk * 64 + w * 16;
  const int m = l & 15, ksub = (l >> 4) * 8;
  float4v acc = {0.f, 0.f, 0.f, 0.f};
  const unsigned short* hs[2] = {h0b, h1b};
#pragma unroll
  for (int a = 0; a < 2; ++a) {
    const unsigned short* __restrict__ H = hs[a];
#pragma unroll
    for (int kk = 0; kk < 4; ++kk) {
      const short8v av = *(const short8v*)(H + (size_t)(row0 + m) * DF + kk * 32 + ksub);
      const short8v bv = *(const short8v*)(RT + m * 384 + a * 128 + kk * 32 + ksub);
      acc = __builtin_amdgcn_mfma_f32_16x16x32_bf16(av, bv, acc, 0, 0, 0);
    }
  }
  const int r0 = row0 + (l >> 4) * 4;
  const float rb = R0b[m] + R1b[m] + R2b[m];
#pragma unroll
  for (int r = 0; r < 4; ++r)
    if (r0 + r < NN) out[(r0 + r) * 16 + m] = acc[r] + rb;
}

// ---------------- stage1: proj L0 first, then GRID-STRIDED hist (XCD-ranged) ---------
// Hist reads the PACKED edge array (one u32 per edge instead of two u32 loads).
__global__ __launch_bounds__(256) void stage1_kernel(
    const unsigned* __restrict__ epk, int* __restrict__ deg,
    unsigned short* __restrict__ ssrcB, const float* __restrict__ Xf,
    unsigned short* __restrict__ XbOut, const unsigned short* __restrict__ WT0,
    _Float16* __restrict__ fsh, _Float16* __restrict__ fdh) {
  __shared__ unsigned short At[64][136];
  const int b = blockIdx.x;
  const int tid = threadIdx.x;
  if (b >= PROJ_BLOCKS) {
    const int range = b & 7;                       // XCD id (blockIdx round-robin)
    const unsigned rlo = range * 6250;
    const int hb = b - PROJ_BLOCKS;
    for (int c = hb >> 3; c < NCHUNK; c += HB_PER_RANGE) {
      const unsigned pk = epk[c * 256 + tid];
      const unsigned dn = pk & 0xffffu;
      if (dn - rlo < 6250u) {
        const int k = atomicAdd(&deg[dn], 1);
        if (k < BCAP) ssrcB[dn * BCAP + k] = (unsigned short)(pk >> 16);
      }
    }
    return;
  }
  proj_body<true>(At, b, tid, nullptr, Xf, XbOut, WT0, fsh, fdh);
}

// ---------------- layer-1 projection + readout01 (both depend only on attn0) --------
__global__ __launch_bounds__(256) void projl1_rd01_kernel(
    const unsigned short* __restrict__ h1b, const unsigned short* __restrict__ WT,
    _Float16* __restrict__ fsh, _Float16* __restrict__ fdh,
    const unsigned short* __restrict__ xb, const unsigned short* __restrict__ RT,
    const float* __restrict__ R0b, const float* __restrict__ R1b,
    const float* __restrict__ R2b, float* __restrict__ out) {
  __shared__ unsigned short At[64][136];
  const int b = blockIdx.x;
  if (b < PROJ_BLOCKS) {
    proj_body<false>(At, b, threadIdx.x, h1b, nullptr, nullptr, WT, fsh, fdh);
  } else {
    readout01_body(b - PROJ_BLOCKS, threadIdx.x, xb, h1b, RT, R0b, R1b, R2b, out);
  }
}

// ---------------- fused attention (fp16, depth-2 pipeline, DPP reduce) ----------------
// One wave per node, both heads. lane = eg(2b)|s16(4b): 16B fp16 load = 8 dims.
// FUSED_RD (layer 1): fold out += h2@R2 into the epilogue; h2b never materializes.
template <bool FUSED_RD>
__global__ __launch_bounds__(256) void csr_attention_kernel(
    const _Float16* __restrict__ fsh, const _Float16* __restrict__ fdh,
    const float* __restrict__ attn, const int* __restrict__ degv,
    const unsigned short* __restrict__ ssrcB, const float* __restrict__ bias,
    unsigned short* __restrict__ houtb, const unsigned short* __restrict__ RT,
    float* __restrict__ out) {
  const int node = (blockIdx.x * 256 + threadIdx.x) >> 6;
  const int lane = threadIdx.x & 63;
  const int eg = lane >> 4, s16 = lane & 15;
  const int deg = min(degv[node], BCAP);
  const unsigned short* __restrict__ sb = ssrcB + node * BCAP;
  const uint4* __restrict__ fsh4 = (const uint4*)fsh;

  half2v fdv[4], at[4];
  {
    const uint4 fq = ((const uint4*)fdh)[node * 16 + s16];
    fdv[0] = __builtin_bit_cast(half2v, fq.x);
    fdv[1] = __builtin_bit_cast(half2v, fq.y);
    fdv[2] = __builtin_bit_cast(half2v, fq.z);
    fdv[3] = __builtin_bit_cast(half2v, fq.w);
    const float4 a0 = ((const float4*)(attn + s16 * 8))[0];
    const float4 a1 = ((const float4*)(attn + s16 * 8))[1];
    const float l2e = 1.44269504f;
    at[0] = (half2v){(_Float16)(a0.x * l2e), (_Float16)(a0.y * l2e)};
    at[1] = (half2v){(_Float16)(a0.z * l2e), (_Float16)(a0.w * l2e)};
    at[2] = (half2v){(_Float16)(a1.x * l2e), (_Float16)(a1.y * l2e)};
    at[3] = (half2v){(_Float16)(a1.z * l2e), (_Float16)(a1.w * l2e)};
  }
  const half2v c02 = {(_Float16)0.2f, (_Float16)0.2f};

  float s = 0.f;
  half2v acc[4] = {{0, 0}, {0, 0}, {0, 0}, {0, 0}};
  const int nfull = deg >> 2;
  const int rem = deg & 3;

  auto consume = [&](const uint4 q) {
    half2v f[4];
    f[0] = __builtin_bit_cast(half2v, q.x);
    f[1] = __builtin_bit_cast(half2v, q.y);
    f[2] = __builtin_bit_cast(half2v, q.z);
    f[3] = __builtin_bit_cast(half2v, q.w);
    float v = 0.f;
#pragma unroll
    for (int k = 0; k < 4; ++k) {
      const half2v t = f[k] + fdv[k];                            // v_pk_add_f16
      const half2v lk = __builtin_elementwise_max(t, t * c02);   // pk_mul + pk_max
      v = __builtin_amdgcn_fdot2(lk, at[k], v, false);           // v_dot2_f32_f16
    }
    v = reduce8_dpp(v);                                          // 3 VALU-dpp adds
    const float p = exp2f(v);
    s += p;
    const _Float16 ph = (_Float16)p;
    const half2v p2 = {ph, ph};
#pragma unroll
    for (int k = 0; k < 4; ++k) acc[k] = p2 * f[k] + acc[k];     // v_pk_fma_f16
  };

  // primer: rows for iters 0,1 in flight; indices for iters 2,3 loaded
  int snA = (int)sb[eg];
  int snB = (int)sb[eg + 4];
  uint4 qA = fsh4[snA * 16 + s16];
  uint4 qB = fsh4[snB * 16 + s16];
  snA = (int)sb[eg + 8];
  snB = (int)sb[eg + 12];

  int base = eg + 16;
  const int npairs = nfull >> 1;
  for (int jj = 0; jj < npairs; ++jj) {
    consume(qA);
    qA = fsh4[snA * 16 + s16];                 // row for iter 2j+2
    snA = (int)sb[base];                       // index for iter 2j+4 (may over-read)
    consume(qB);
    qB = fsh4[snB * 16 + s16];                 // row for iter 2j+3
    snB = (int)sb[base + 4];                   // index for iter 2j+5 (may over-read)
    base += 8;
  }
  if (nfull & 1) {  // peel the odd full iteration; tail row then sits in qB
    consume(qA);
    qA = qB;
  }
  if (rem) {  // tail: qA holds row for edge eg + 4*nfull (junk-but-finite if eg >= rem)
    half2v f[4];
    f[0] = __builtin_bit_cast(half2v, qA.x);
    f[1] = __builtin_bit_cast(half2v, qA.y);
    f[2] = __builtin_bit_cast(half2v, qA.z);
    f[3] = __builtin_bit_cast(half2v, qA.w);
    float v = 0.f;
#pragma unroll
    for (int k = 0; k < 4; ++k) {
      const half2v t = f[k] + fdv[k];
      const half2v lk = __builtin_elementwise_max(t, t * c02);
      v = __builtin_amdgcn_fdot2(lk, at[k], v, false);
    }
    v = reduce8_dpp(v);
    const float p = (eg < rem) ? exp2f(v) : 0.f;                 // guard zeroes junk
    s += p;
    const _Float16 ph = (_Float16)p;
    const half2v p2 = {ph, ph};
#pragma unroll
    for (int k = 0; k < 4; ++k) acc[k] = p2 * f[k] + acc[k];
  }

  // merge the 4 edge groups (one 32-bit shfl moves 2 dims)
#pragma unroll
  for (int dist = 16; dist <= 32; dist <<= 1) {
    s += __shfl_xor(s, dist);
#pragma unroll
    for (int k = 0; k < 4; ++k) {
      const float of = __shfl_xor(__builtin_bit_cast(float, acc[k]), dist);
      acc[k] = acc[k] + __builtin_bit_cast(half2v, of);
    }
  }

  // epilogue: all lanes hold the merged row slice for dims d = s16*8 + j
  const float rs = (deg > 0) ? 1.0f / s : 0.0f;
  const float4 b0 = ((const float4*)(bias + s16 * 8))[0];
  const float4 b1 = ((const float4*)(bias + s16 * 8))[1];
  const float bb[8] = {b0.x, b0.y, b0.z, b0.w, b1.x, b1.y, b1.z, b1.w};
  float ob[8];
#pragma unroll
  for (int k = 0; k < 4; ++k) {
    ob[2 * k]     = leaky(fmaf((float)acc[k].x, rs, bb[2 * k]));
    ob[2 * k + 1] = leaky(fmaf((float)acc[k].y, rs, bb[2 * k + 1]));
  }

  if constexpr (!FUSED_RD) {
    if (lane < 16) {
      uint4 w;
      w.x = rne_bf16(ob[0]) | ((unsigned)rne_bf16(ob[1]) << 16);
      w.y = rne_bf16(ob[2]) | ((unsigned)rne_bf16(ob[3]) << 16);
      w.z = rne_bf16(ob[4]) | ((unsigned)rne_bf16(ob[5]) << 16);
      w.w = rne_bf16(ob[6]) | ((unsigned)rne_bf16(ob[7]) << 16);
      ((uint4*)houtb)[node * 16 + s16] = w;
    }
  } else {
    // out[node][c] += sum_d ob_row[d] * R2[d][c]; lane covers c = eg*4+cc, d = s16*8+j
    float rsum[4];
#pragma unroll
    for (int cc = 0; cc < 4; ++cc) {
      const short8v rv = *(const short8v*)(RT + (eg * 4 + cc) * 384 + 256 + s16 * 8);
      float t = 0.f;
#pragma unroll
      for (int j = 0; j < 8; ++j)
        t = fmaf(__uint_as_float(((unsigned)(unsigned short)rv[j]) << 16), ob[j], t);
      rsum[cc] = reduce16_dpp(t);
    }
    if (s16 == 0) {
      float4* o4 = (float4*)(out + node * 16 + eg * 4);
      float4 cur = *o4;
      cur.x += rsum[0];
      cur.y += rsum[1];
      cur.z += rsum[2];
      cur.w += rsum[3];
      *o4 = cur;
    }
  }
}

extern "C" void kernel_launch(void* const* d_in, const int* in_sizes, int n_in,
                              void* d_out, int out_size, void* d_ws, size_t ws_size,
                              hipStream_t stream) {
  const float* x     = (const float*)d_in[0];
  const int*   src   = (const int*)d_in[1];
  const int*   dst   = (const int*)d_in[2];
  const float* Wsrc0 = (const float*)d_in[3];
  const float* Wdst0 = (const float*)d_in[4];
  const float* attn0 = (const float*)d_in[5];
  const float* bias0 = (const float*)d_in[6];
  const float* Wsrc1 = (const float*)d_in[7];
  const float* Wdst1 = (const float*)d_in[8];
  const float* attn1 = (const float*)d_in[9];
  const float* bias1 = (const float*)d_in[10];
  const float* R0W   = (const float*)d_in[11];
  const float* R0b   = (const float*)d_in[12];
  const float* R1W   = (const float*)d_in[13];
  const float* R1b   = (const float*)d_in[14];
  const float* R2W   = (const float*)d_in[15];
  const float* R2b   = (const float*)d_in[16];
  float* out = (float*)d_out;

  // workspace: xb | h1b (NNP rows bf16) | fsh | fdh (NN rows fp16) | WT0 | WT1 | RT
  //            | deg (int) | ssrcB (+512 pad, u16) | epk (u32)   ~= 61 MB
  unsigned short* xb  = (unsigned short*)d_ws;
  unsigned short* h1b = xb + (size_t)NNP * DF;
  _Float16* fsh = (_Float16*)(h1b + (size_t)NNP * DF);
  _Float16* fdh = fsh + (size_t)NN * DF;
  unsigned short* WT0 = (unsigned short*)(fdh + (size_t)NN * DF);
  unsigned short* WT1 = WT0 + 256 * DF;
  unsigned short* RT  = WT1 + 256 * DF;
  int* deg = (int*)(RT + 16 * 384);
  unsigned short* ssrcB = (unsigned short*)(deg + NN);
  unsigned* epk = (unsigned*)(ssrcB + (size_t)NN * BCAP + 512);

  // ---- launch 1: zero deg + weight casts + edge pack ----
  prep_kernel<<<476 + NCHUNK, 256, 0, stream>>>(deg, Wsrc0, Wdst0, Wsrc1, Wdst1, WT0, WT1,
                                                R0W, R1W, R2W, RT, src, dst, epk);

  // ---- launch 2: proj L0 (blocks 0..781) + grid-strided hist (XCD-ranged, packed) ----
  stage1_kernel<<<PROJ_BLOCKS + HF_BLOCKS, 256, 0, stream>>>(
      epk, deg, ssrcB, x, xb, WT0, fsh, fdh);

  // ---- launch 3: layer 0 attention -> h1b ----
  csr_attention_kernel<false><<<(NN * 64) / 256, 256, 0, stream>>>(
      fsh, fdh, attn0, deg, ssrcB, bias0, h1b, nullptr, nullptr);

  // ---- launch 4: layer 1 projection + readout01 (out = xb@R0 + h1b@R1 + biases) ----
  projl1_rd01_kernel<<<2 * PROJ_BLOCKS, 256, 0, stream>>>(
      h1b, WT1, fsh, fdh, xb, RT, R0b, R1b, R2b, out);

  // ---- launch 5: layer 1 attention with fused out += h2@R2 (h2 never materialized) --
  csr_attention_kernel<true><<<(NN * 64) / 256, 256, 0, stream>>>(
      fsh, fdh, attn1, deg, ssrcB, bias1, nullptr, RT, out);
}

// Round 21
// 141.733 us; speedup vs baseline: 1.0677x; 1.0101x over previous
//
#include <hip/hip_runtime.h>

#define NN 50000
#define NNP 50048  // padded row count (multiple of 64) for MFMA kernels
#define NE 800000
#define DF 128     // H * D_HID == D_IN
#define BCAP 64    // per-node edge bucket capacity (deg ~ Poisson(16): P(>64) ~ 0)
#define NCHUNK (NE / 256)              // 3125 edge chunks of 256
#define HB_PER_RANGE 256               // hist blocks per dst-range (13 iters/block)
#define HF_BLOCKS (HB_PER_RANGE * 8)   // 2048 grid-strided hist blocks
#define PROJ_BLOCKS ((NN + 63) / 64)   // 782 (64-row tiles)

typedef __attribute__((ext_vector_type(8))) short short8v;    // 8 bf16 (4 VGPRs)
typedef __attribute__((ext_vector_type(4))) float float4v;    // MFMA acc
typedef __attribute__((ext_vector_type(2))) _Float16 half2v;  // packed fp16 pair

__device__ __forceinline__ float leaky(float t) { return fmaxf(t, 0.2f * t); }

__device__ __forceinline__ unsigned short rne_bf16(float x) {
  unsigned u = __float_as_uint(x);
  u = (u + 0x7fffu + ((u >> 16) & 1u)) >> 16;
  return (unsigned short)u;
}

// f32 add over DPP lane-permute (full-rate VALU; avoids ds_bpermute latency)
template <int CTRL>
__device__ __forceinline__ float dpp_add(float v) {
  const int i = __builtin_bit_cast(int, v);
  const int p = __builtin_amdgcn_update_dpp(0, i, CTRL, 0xF, 0xF, true);
  return v + __builtin_bit_cast(float, p);
}
// sum over 8 contiguous lanes: xor1 (0xB1), xor2 (0x4E), row_half_mirror (0x141)
__device__ __forceinline__ float reduce8_dpp(float v) {
  v = dpp_add<0xB1>(v);
  v = dpp_add<0x4E>(v);
  v = dpp_add<0x141>(v);
  return v;
}
// sum over 16 contiguous lanes (one DPP row): reduce8 + row_mirror (0x140)
__device__ __forceinline__ float reduce16_dpp(float v) {
  v = reduce8_dpp(v);
  v = dpp_add<0x140>(v);
  return v;
}

// ---------------- prep: zero deg + weight casts + edge pack ----------------
// blocks [0,196) zero deg; [196,452) WT casts; [452,476) RT casts;
// [476, 476+NCHUNK): pack epk[e] = dst | (src<<16)  (both < 2^16)
__global__ void prep_kernel(int* __restrict__ deg,
                            const float* __restrict__ Ws0, const float* __restrict__ Wd0,
                            const float* __restrict__ Ws1, const float* __restrict__ Wd1,
                            unsigned short* __restrict__ WT0, unsigned short* __restrict__ WT1,
                            const float* __restrict__ R0W, const float* __restrict__ R1W,
                            const float* __restrict__ R2W, unsigned short* __restrict__ RT,
                            const int* __restrict__ src, const int* __restrict__ dst,
                            unsigned* __restrict__ epk) {
  const int b = blockIdx.x;
  const int tid = threadIdx.x;
  if (b < 196) {
    const int i = b * 256 + tid;
    if (i < NN) deg[i] = 0;
  } else if (b < 452) {                // WT[l][256][128]: row c<128 -> Wsrc col c, else Wdst
    const int idx = (b - 196) * 256 + tid;   // 0..65535
    const int l = idx >> 15;
    const int r = (idx >> 7) & 255;
    const int k = idx & 127;
    const float* Ws = l ? Ws1 : Ws0;
    const float* Wd = l ? Wd1 : Wd0;
    const float v = (r < 128) ? Ws[k * DF + r] : Wd[k * DF + (r - 128)];
    (l ? WT1 : WT0)[r * DF + k] = rne_bf16(v);
  } else if (b < 476) {                // RT[16][384]
    const int idx = (b - 452) * 256 + tid;   // 0..6143
    const int c = idx / 384, k = idx - c * 384;
    const float* Rw = (k < 128) ? R0W : (k < 256) ? R1W : R2W;
    RT[c * 384 + k] = rne_bf16(Rw[(k & 127) * 16 + c]);
  } else {                             // edge pack
    const int e = (b - 476) * 256 + tid;
    epk[e] = (unsigned)dst[e] | ((unsigned)src[e] << 16);
  }
}

// ---------------- shared MFMA projection body, 64-row tiles ----------------
// L0: f32 input, casts into LDS, and fuses out-init = x@R0 + all biases
// (the bf16 x tile lives in LDS; xb never materializes).
template <bool L0>
__device__ __forceinline__ void proj_body(unsigned short (*At)[136], int blk, int tid,
                                          const unsigned short* __restrict__ Ab,
                                          const float* __restrict__ Xf,
                                          const unsigned short* __restrict__ WT,
                                          _Float16* __restrict__ fsh,
                                          _Float16* __restrict__ fdh,
                                          const unsigned short* __restrict__ RT,
                                          const float* __restrict__ R0b,
                                          const float* __restrict__ R1b,
                                          const float* __restrict__ R2b,
                                          float* __restrict__ out) {
  const int w = tid >> 6, l = tid & 63;

#pragma unroll
  for (int i = 0; i < 4; ++i) {
    const int flat = i * 256 + tid;
    const int r = flat >> 4, c16 = flat & 15;
    const int row = blk * 64 + r;
    uint4 v = make_uint4(0, 0, 0, 0);
    if (L0) {
      if (row < NN) {
        const float4 a = ((const float4*)Xf)[row * 32 + c16 * 2];
        const float4 bq = ((const float4*)Xf)[row * 32 + c16 * 2 + 1];
        v.x = rne_bf16(a.x) | ((unsigned)rne_bf16(a.y) << 16);
        v.y = rne_bf16(a.z) | ((unsigned)rne_bf16(a.w) << 16);
        v.z = rne_bf16(bq.x) | ((unsigned)rne_bf16(bq.y) << 16);
        v.w = rne_bf16(bq.z) | ((unsigned)rne_bf16(bq.w) << 16);
      }
    } else {
      if (row < NN) v = ((const uint4*)Ab)[row * 16 + c16];
    }
    *(uint4*)&At[r][c16 * 8] = v;
  }

  const int kof = (l >> 4) * 8;
  const int cbase = w * 64 + (l & 15);
  short8v b[4][4];
#pragma unroll
  for (int ct = 0; ct < 4; ++ct)
#pragma unroll
    for (int kk = 0; kk < 4; ++kk)
      b[ct][kk] = *(const short8v*)(WT + (cbase + ct * 16) * DF + kk * 32 + kof);
  __syncthreads();

  const int lrow = l & 15;
#pragma unroll
  for (int rt = 0; rt < 4; ++rt) {
    short8v a[4];
#pragma unroll
    for (int kk = 0; kk < 4; ++kk) a[kk] = *(const short8v*)&At[rt * 16 + lrow][kk * 32 + kof];
    const int r0 = blk * 64 + rt * 16 + (l >> 4) * 4;
#pragma unroll
    for (int ct = 0; ct < 4; ++ct) {
      float4v acc = {0.f, 0.f, 0.f, 0.f};
#pragma unroll
      for (int kk = 0; kk < 4; ++kk)
        acc = __builtin_amdgcn_mfma_f32_16x16x32_bf16(a[kk], b[ct][kk], acc, 0, 0, 0);
      const int col = cbase + ct * 16;
      _Float16* O = (col < DF) ? fsh : fdh;
      const int c2 = (col < DF) ? col : col - DF;
#pragma unroll
      for (int r = 0; r < 4; ++r)
        if (r0 + r < NN) O[(r0 + r) * DF + c2] = (_Float16)acc[r];
    }
  }

  if (L0) {
    // fused out-init: out[row][c] = At_row @ R0[.][c] + (R0b+R1b+R2b)[c]
    // wave w handles row-tile w (rows blk*64 + w*16 ..); 4 MFMA + 4 stores per wave.
    float4v racc = {0.f, 0.f, 0.f, 0.f};
#pragma unroll
    for (int kk = 0; kk < 4; ++kk) {
      const short8v av = *(const short8v*)&At[w * 16 + lrow][kk * 32 + kof];
      const short8v bv = *(const short8v*)(RT + lrow * 384 + kk * 32 + kof);
      racc = __builtin_amdgcn_mfma_f32_16x16x32_bf16(av, bv, racc, 0, 0, 0);
    }
    const int r0 = blk * 64 + w * 16 + (l >> 4) * 4;
    const float rb = R0b[lrow] + R1b[lrow] + R2b[lrow];
#pragma unroll
    for (int r = 0; r < 4; ++r)
      if (r0 + r < NN) out[(r0 + r) * 16 + lrow] = racc[r] + rb;
  }
}

// ---------------- readout1 body: out += h1b @ R1 ----------------
__device__ __forceinline__ void readout1_body(int blk, int tid,
                                              const unsigned short* __restrict__ h1b,
                                              const unsigned short* __restrict__ RT,
                                              float* __restrict__ out) {
  const int w = tid >> 6, l = tid & 63;
  const int row0 = blk * 64 + w * 16;
  const int m = l & 15, ksub = (l >> 4) * 8;
  float4v acc = {0.f, 0.f, 0.f, 0.f};
#pragma unroll
  for (int kk = 0; kk < 4; ++kk) {
    const short8v av = *(const short8v*)(h1b + (size_t)(row0 + m) * DF + kk * 32 + ksub);
    const short8v bv = *(const short8v*)(RT + m * 384 + 128 + kk * 32 + ksub);
    acc = __builtin_amdgcn_mfma_f32_16x16x32_bf16(av, bv, acc, 0, 0, 0);
  }
  const int r0 = row0 + (l >> 4) * 4;
#pragma unroll
  for (int r = 0; r < 4; ++r)
    if (r0 + r < NN) out[(r0 + r) * 16 + m] += acc[r];
}

// ---------------- stage1: proj L0 (+out init) first, then GRID-STRIDED hist ---------
__global__ __launch_bounds__(256) void stage1_kernel(
    const unsigned* __restrict__ epk, int* __restrict__ deg,
    unsigned short* __restrict__ ssrcB, const float* __restrict__ Xf,
    const unsigned short* __restrict__ WT0, _Float16* __restrict__ fsh,
    _Float16* __restrict__ fdh, const unsigned short* __restrict__ RT,
    const float* __restrict__ R0b, const float* __restrict__ R1b,
    const float* __restrict__ R2b, float* __restrict__ out) {
  __shared__ unsigned short At[64][136];
  const int b = blockIdx.x;
  const int tid = threadIdx.x;
  if (b >= PROJ_BLOCKS) {
    const int range = b & 7;                       // XCD id (blockIdx round-robin)
    const unsigned rlo = range * 6250;
    const int hb = b - PROJ_BLOCKS;
    for (int c = hb >> 3; c < NCHUNK; c += HB_PER_RANGE) {
      const unsigned pk = epk[c * 256 + tid];
      const unsigned dn = pk & 0xffffu;
      if (dn - rlo < 6250u) {
        const int k = atomicAdd(&deg[dn], 1);
        if (k < BCAP) ssrcB[dn * BCAP + k] = (unsigned short)(pk >> 16);
      }
    }
    return;
  }
  proj_body<true>(At, b, tid, nullptr, Xf, WT0, fsh, fdh, RT, R0b, R1b, R2b, out);
}

// ---------------- layer-1 projection + readout1 (both depend only on attn0) --------
__global__ __launch_bounds__(256) void projl1_rd1_kernel(
    const unsigned short* __restrict__ h1b, const unsigned short* __restrict__ WT,
    _Float16* __restrict__ fsh, _Float16* __restrict__ fdh,
    const unsigned short* __restrict__ RT, float* __restrict__ out) {
  __shared__ unsigned short At[64][136];
  const int b = blockIdx.x;
  if (b < PROJ_BLOCKS) {
    proj_body<false>(At, b, threadIdx.x, h1b, nullptr, WT, fsh, fdh,
                     nullptr, nullptr, nullptr, nullptr, nullptr);
  } else {
    readout1_body(b - PROJ_BLOCKS, threadIdx.x, h1b, RT, out);
  }
}

// ---------------- fused attention (fp16, depth-2 pipeline, DPP reduce) ----------------
// One wave per node, both heads. lane = eg(2b)|s16(4b): 16B fp16 load = 8 dims.
// FUSED_RD (layer 1): fold out += h2@R2 into the epilogue; h2b never materializes.
template <bool FUSED_RD>
__global__ __launch_bounds__(256) void csr_attention_kernel(
    const _Float16* __restrict__ fsh, const _Float16* __restrict__ fdh,
    const float* __restrict__ attn, const int* __restrict__ degv,
    const unsigned short* __restrict__ ssrcB, const float* __restrict__ bias,
    unsigned short* __restrict__ houtb, const unsigned short* __restrict__ RT,
    float* __restrict__ out) {
  const int node = (blockIdx.x * 256 + threadIdx.x) >> 6;
  const int lane = threadIdx.x & 63;
  const int eg = lane >> 4, s16 = lane & 15;
  const int deg = min(degv[node], BCAP);
  const unsigned short* __restrict__ sb = ssrcB + node * BCAP;
  const uint4* __restrict__ fsh4 = (const uint4*)fsh;

  half2v fdv[4], at[4];
  {
    const uint4 fq = ((const uint4*)fdh)[node * 16 + s16];
    fdv[0] = __builtin_bit_cast(half2v, fq.x);
    fdv[1] = __builtin_bit_cast(half2v, fq.y);
    fdv[2] = __builtin_bit_cast(half2v, fq.z);
    fdv[3] = __builtin_bit_cast(half2v, fq.w);
    const float4 a0 = ((const float4*)(attn + s16 * 8))[0];
    const float4 a1 = ((const float4*)(attn + s16 * 8))[1];
    const float l2e = 1.44269504f;
    at[0] = (half2v){(_Float16)(a0.x * l2e), (_Float16)(a0.y * l2e)};
    at[1] = (half2v){(_Float16)(a0.z * l2e), (_Float16)(a0.w * l2e)};
    at[2] = (half2v){(_Float16)(a1.x * l2e), (_Float16)(a1.y * l2e)};
    at[3] = (half2v){(_Float16)(a1.z * l2e), (_Float16)(a1.w * l2e)};
  }
  const half2v c02 = {(_Float16)0.2f, (_Float16)0.2f};

  float s = 0.f;
  half2v acc[4] = {{0, 0}, {0, 0}, {0, 0}, {0, 0}};
  const int nfull = deg >> 2;
  const int rem = deg & 3;

  auto consume = [&](const uint4 q) {
    half2v f[4];
    f[0] = __builtin_bit_cast(half2v, q.x);
    f[1] = __builtin_bit_cast(half2v, q.y);
    f[2] = __builtin_bit_cast(half2v, q.z);
    f[3] = __builtin_bit_cast(half2v, q.w);
    float v = 0.f;
#pragma unroll
    for (int k = 0; k < 4; ++k) {
      const half2v t = f[k] + fdv[k];                            // v_pk_add_f16
      const half2v lk = __builtin_elementwise_max(t, t * c02);   // pk_mul + pk_max
      v = __builtin_amdgcn_fdot2(lk, at[k], v, false);           // v_dot2_f32_f16
    }
    v = reduce8_dpp(v);                                          // 3 VALU-dpp adds
    const float p = exp2f(v);
    s += p;
    const _Float16 ph = (_Float16)p;
    const half2v p2 = {ph, ph};
#pragma unroll
    for (int k = 0; k < 4; ++k) acc[k] = p2 * f[k] + acc[k];     // v_pk_fma_f16
  };

  // primer: rows for iters 0,1 in flight; indices for iters 2,3 loaded
  int snA = (int)sb[eg];
  int snB = (int)sb[eg + 4];
  uint4 qA = fsh4[snA * 16 + s16];
  uint4 qB = fsh4[snB * 16 + s16];
  snA = (int)sb[eg + 8];
  snB = (int)sb[eg + 12];

  int base = eg + 16;
  const int npairs = nfull >> 1;
  for (int jj = 0; jj < npairs; ++jj) {
    consume(qA);
    qA = fsh4[snA * 16 + s16];                 // row for iter 2j+2
    snA = (int)sb[base];                       // index for iter 2j+4 (may over-read)
    consume(qB);
    qB = fsh4[snB * 16 + s16];                 // row for iter 2j+3
    snB = (int)sb[base + 4];                   // index for iter 2j+5 (may over-read)
    base += 8;
  }
  if (nfull & 1) {  // peel the odd full iteration; tail row then sits in qB
    consume(qA);
    qA = qB;
  }
  if (rem) {  // tail: qA holds row for edge eg + 4*nfull (junk-but-finite if eg >= rem)
    half2v f[4];
    f[0] = __builtin_bit_cast(half2v, qA.x);
    f[1] = __builtin_bit_cast(half2v, qA.y);
    f[2] = __builtin_bit_cast(half2v, qA.z);
    f[3] = __builtin_bit_cast(half2v, qA.w);
    float v = 0.f;
#pragma unroll
    for (int k = 0; k < 4; ++k) {
      const half2v t = f[k] + fdv[k];
      const half2v lk = __builtin_elementwise_max(t, t * c02);
      v = __builtin_amdgcn_fdot2(lk, at[k], v, false);
    }
    v = reduce8_dpp(v);
    const float p = (eg < rem) ? exp2f(v) : 0.f;                 // guard zeroes junk
    s += p;
    const _Float16 ph = (_Float16)p;
    const half2v p2 = {ph, ph};
#pragma unroll
    for (int k = 0; k < 4; ++k) acc[k] = p2 * f[k] + acc[k];
  }

  // merge the 4 edge groups (one 32-bit shfl moves 2 dims)
#pragma unroll
  for (int dist = 16; dist <= 32; dist <<= 1) {
    s += __shfl_xor(s, dist);
#pragma unroll
    for (int k = 0; k < 4; ++k) {
      const float of = __shfl_xor(__builtin_bit_cast(float, acc[k]), dist);
      acc[k] = acc[k] + __builtin_bit_cast(half2v, of);
    }
  }

  // epilogue: all lanes hold the merged row slice for dims d = s16*8 + j
  const float rs = (deg > 0) ? 1.0f / s : 0.0f;
  const float4 b0 = ((const float4*)(bias + s16 * 8))[0];
  const float4 b1 = ((const float4*)(bias + s16 * 8))[1];
  const float bb[8] = {b0.x, b0.y, b0.z, b0.w, b1.x, b1.y, b1.z, b1.w};
  float ob[8];
#pragma unroll
  for (int k = 0; k < 4; ++k) {
    ob[2 * k]     = leaky(fmaf((float)acc[k].x, rs, bb[2 * k]));
    ob[2 * k + 1] = leaky(fmaf((float)acc[k].y, rs, bb[2 * k + 1]));
  }

  if constexpr (!FUSED_RD) {
    if (lane < 16) {
      uint4 w;
      w.x = rne_bf16(ob[0]) | ((unsigned)rne_bf16(ob[1]) << 16);
      w.y = rne_bf16(ob[2]) | ((unsigned)rne_bf16(ob[3]) << 16);
      w.z = rne_bf16(ob[4]) | ((unsigned)rne_bf16(ob[5]) << 16);
      w.w = rne_bf16(ob[6]) | ((unsigned)rne_bf16(ob[7]) << 16);
      ((uint4*)houtb)[node * 16 + s16] = w;
    }
  } else {
    // out[node][c] += sum_d ob_row[d] * R2[d][c]; lane covers c = eg*4+cc, d = s16*8+j
    float rsum[4];
#pragma unroll
    for (int cc = 0; cc < 4; ++cc) {
      const short8v rv = *(const short8v*)(RT + (eg * 4 + cc) * 384 + 256 + s16 * 8);
      float t = 0.f;
#pragma unroll
      for (int j = 0; j < 8; ++j)
        t = fmaf(__uint_as_float(((unsigned)(unsigned short)rv[j]) << 16), ob[j], t);
      rsum[cc] = reduce16_dpp(t);
    }
    if (s16 == 0) {
      float4* o4 = (float4*)(out + node * 16 + eg * 4);
      float4 cur = *o4;
      cur.x += rsum[0];
      cur.y += rsum[1];
      cur.z += rsum[2];
      cur.w += rsum[3];
      *o4 = cur;
    }
  }
}

extern "C" void kernel_launch(void* const* d_in, const int* in_sizes, int n_in,
                              void* d_out, int out_size, void* d_ws, size_t ws_size,
                              hipStream_t stream) {
  const float* x     = (const float*)d_in[0];
  const int*   src   = (const int*)d_in[1];
  const int*   dst   = (const int*)d_in[2];
  const float* Wsrc0 = (const float*)d_in[3];
  const float* Wdst0 = (const float*)d_in[4];
  const float* attn0 = (const float*)d_in[5];
  const float* bias0 = (const float*)d_in[6];
  const float* Wsrc1 = (const float*)d_in[7];
  const float* Wdst1 = (const float*)d_in[8];
  const float* attn1 = (const float*)d_in[9];
  const float* bias1 = (const float*)d_in[10];
  const float* R0W   = (const float*)d_in[11];
  const float* R0b   = (const float*)d_in[12];
  const float* R1W   = (const float*)d_in[13];
  const float* R1b   = (const float*)d_in[14];
  const float* R2W   = (const float*)d_in[15];
  const float* R2b   = (const float*)d_in[16];
  float* out = (float*)d_out;

  // workspace: h1b (NNP rows bf16) | fsh | fdh (NN rows fp16) | WT0 | WT1 | RT
  //            | deg (int) | ssrcB (+512 pad, u16) | epk (u32)   ~= 48 MB
  unsigned short* h1b = (unsigned short*)d_ws;
  _Float16* fsh = (_Float16*)(h1b + (size_t)NNP * DF);
  _Float16* fdh = fsh + (size_t)NN * DF;
  unsigned short* WT0 = (unsigned short*)(fdh + (size_t)NN * DF);
  unsigned short* WT1 = WT0 + 256 * DF;
  unsigned short* RT  = WT1 + 256 * DF;
  int* deg = (int*)(RT + 16 * 384);
  unsigned short* ssrcB = (unsigned short*)(deg + NN);
  unsigned* epk = (unsigned*)(ssrcB + (size_t)NN * BCAP + 512);

  // ---- launch 1: zero deg + weight casts + edge pack ----
  prep_kernel<<<476 + NCHUNK, 256, 0, stream>>>(deg, Wsrc0, Wdst0, Wsrc1, Wdst1, WT0, WT1,
                                                R0W, R1W, R2W, RT, src, dst, epk);

  // ---- launch 2: proj L0 (+ out = x@R0 + biases) + grid-strided hist ----
  stage1_kernel<<<PROJ_BLOCKS + HF_BLOCKS, 256, 0, stream>>>(
      epk, deg, ssrcB, x, WT0, fsh, fdh, RT, R0b, R1b, R2b, out);

  // ---- launch 3: layer 0 attention -> h1b ----
  csr_attention_kernel<false><<<(NN * 64) / 256, 256, 0, stream>>>(
      fsh, fdh, attn0, deg, ssrcB, bias0, h1b, nullptr, nullptr);

  // ---- launch 4: layer 1 projection + readout1 (out += h1b@R1) ----
  projl1_rd1_kernel<<<2 * PROJ_BLOCKS, 256, 0, stream>>>(h1b, WT1, fsh, fdh, RT, out);

  // ---- launch 5: layer 1 attention with fused out += h2@R2 (h2 never materialized) --
  csr_attention_kernel<true><<<(NN * 64) / 256, 256, 0, stream>>>(
      fsh, fdh, attn1, deg, ssrcB, bias1, nullptr, RT, out);
}